// Round 1
// baseline (2434.529 us; speedup 1.0000x reference)
//
#include <hip/hip_runtime.h>
#include <hip/hip_bf16.h>
#include <math.h>

#define B_ 2
#define T_ 2048
#define H_ 6
#define DK_ 256
#define DV_ 256
#define HID_ 2048

// ---------------------------------------------------------------------------
// Kernel 1: fused projections
//   beta  = sigmoid(hidden_ab . b_w[n])
//   g     = -exp(A_log[n]) * softplus(hidden_ab . a_w[n] + dt_bias[n])
//   sgate = swish(hidden_g . g_w[n])        (swish applied here already)
// One block per (b,t); 256 threads x 8 elements = 2048 hidden dims.
// ---------------------------------------------------------------------------
__global__ __launch_bounds__(256) void gdn_proj_kernel(
    const float* __restrict__ hab, const float* __restrict__ hg,
    const float* __restrict__ b_w, const float* __restrict__ a_w,
    const float* __restrict__ g_w, const float* __restrict__ A_log,
    const float* __restrict__ dt_bias,
    float* __restrict__ beta_o, float* __restrict__ g_o,
    float* __restrict__ sgate_o) {
  const int bt = blockIdx.x;
  const int tid = threadIdx.x;
  const int lane = tid & 63;
  const int wid = tid >> 6;

  const float* h1 = hab + (size_t)bt * HID_ + tid * 8;
  const float* h2 = hg + (size_t)bt * HID_ + tid * 8;
  const float4 xa = *(const float4*)(h1);
  const float4 xb = *(const float4*)(h1 + 4);
  const float4 ya = *(const float4*)(h2);
  const float4 yb = *(const float4*)(h2 + 4);

  float part[18];
#pragma unroll
  for (int n = 0; n < 6; ++n) {
    const float* wp = b_w + n * HID_ + tid * 8;
    const float4 w0 = *(const float4*)(wp);
    const float4 w1 = *(const float4*)(wp + 4);
    part[n] = xa.x * w0.x + xa.y * w0.y + xa.z * w0.z + xa.w * w0.w +
              xb.x * w1.x + xb.y * w1.y + xb.z * w1.z + xb.w * w1.w;
  }
#pragma unroll
  for (int n = 0; n < 6; ++n) {
    const float* wp = a_w + n * HID_ + tid * 8;
    const float4 w0 = *(const float4*)(wp);
    const float4 w1 = *(const float4*)(wp + 4);
    part[6 + n] = xa.x * w0.x + xa.y * w0.y + xa.z * w0.z + xa.w * w0.w +
                  xb.x * w1.x + xb.y * w1.y + xb.z * w1.z + xb.w * w1.w;
  }
#pragma unroll
  for (int n = 0; n < 6; ++n) {
    const float* wp = g_w + n * HID_ + tid * 8;
    const float4 w0 = *(const float4*)(wp);
    const float4 w1 = *(const float4*)(wp + 4);
    part[12 + n] = ya.x * w0.x + ya.y * w0.y + ya.z * w0.z + ya.w * w0.w +
                   yb.x * w1.x + yb.y * w1.y + yb.z * w1.z + yb.w * w1.w;
  }

  __shared__ float red[18][4];
#pragma unroll
  for (int i = 0; i < 18; ++i) {
    float x = part[i];
    x += __shfl_xor(x, 1);
    x += __shfl_xor(x, 2);
    x += __shfl_xor(x, 4);
    x += __shfl_xor(x, 8);
    x += __shfl_xor(x, 16);
    x += __shfl_xor(x, 32);
    if (lane == 0) red[i][wid] = x;
  }
  __syncthreads();

  if (tid < 18) {
    const float s = red[tid][0] + red[tid][1] + red[tid][2] + red[tid][3];
    if (tid < 6) {
      // beta
      beta_o[(size_t)bt * H_ + tid] = 1.f / (1.f + __expf(-s));
    } else if (tid < 12) {
      const int n = tid - 6;
      const float x = s + dt_bias[n];
      const float sp = (x > 20.f) ? x : log1pf(__expf(x));
      g_o[(size_t)bt * H_ + n] = -__expf(A_log[n]) * sp;
    } else {
      const int n = tid - 12;
      // swish(gate) = gate * sigmoid(gate)
      sgate_o[(size_t)bt * H_ + n] = s / (1.f + __expf(-s));
    }
  }
}

// ---------------------------------------------------------------------------
// Kernel 2: q/k inverse L2 norms (scalars), folded scaling for the scan.
//   sq = rsqrt(sum q^2 + 1e-6) * DK^-0.5 ;  sk = rsqrt(sum k^2 + 1e-6)
// One wave per (b,t,h).
// ---------------------------------------------------------------------------
__global__ __launch_bounds__(256) void gdn_norm_kernel(
    const float* __restrict__ q, const float* __restrict__ k,
    float* __restrict__ sq, float* __restrict__ sk) {
  const int gw = blockIdx.x * 4 + (threadIdx.x >> 6);  // (b*T+t)*H + h
  const int lane = threadIdx.x & 63;

  const float4 qv = *(const float4*)(q + (size_t)gw * DK_ + lane * 4);
  const float4 kv = *(const float4*)(k + (size_t)gw * DK_ + lane * 4);
  float sums_q = qv.x * qv.x + qv.y * qv.y + qv.z * qv.z + qv.w * qv.w;
  float sums_k = kv.x * kv.x + kv.y * kv.y + kv.z * kv.z + kv.w * kv.w;
#pragma unroll
  for (int m = 1; m < 64; m <<= 1) {
    sums_q += __shfl_xor(sums_q, m);
    sums_k += __shfl_xor(sums_k, m);
  }
  if (lane == 0) {
    sq[gw] = rsqrtf(sums_q + 1e-6f) * 0.0625f;  // * DK^-0.5
    sk[gw] = rsqrtf(sums_k + 1e-6f);
  }
}

// ---------------------------------------------------------------------------
// Kernel 3: gated delta-rule scan.
// Grid: B*H*16 blocks; block (b,h,vc) owns 16 state columns S[:, vc*16..+15].
// 256 threads: r = tid&15 (k subgroup), c = tid>>4 (column). Thread holds
// S[16*j + r][vc*16 + c] for j=0..15 in registers. k/q/v/scalars staged in
// LDS, double-buffered, one __syncthreads per step.
// ---------------------------------------------------------------------------
__global__ __launch_bounds__(256) void gdn_scan_kernel(
    const float* __restrict__ q, const float* __restrict__ k,
    const float* __restrict__ v, const float* __restrict__ beta,
    const float* __restrict__ g, const float* __restrict__ sq,
    const float* __restrict__ sk, float* __restrict__ o_raw) {
  const int blk = blockIdx.x;
  const int vc = blk & 15;
  const int bh = blk >> 4;  // b*H + h
  const int tid = threadIdx.x;
  const int r = tid & 15;
  const int c = tid >> 4;

  const int b = bh / H_;
  const int h = bh % H_;
  const size_t base0 = ((size_t)b * T_ * H_ + h) * DK_;  // t=0 element base
  const size_t tstride = (size_t)H_ * DK_;               // per-t stride
  const size_t sbase0 = (size_t)b * T_ * H_ + h;         // scalar arrays

  __shared__ float bk[2][DK_];
  __shared__ float bq[2][DK_];
  __shared__ float bv[2][16];
  __shared__ float bs[2][4];

  float s[16];
#pragma unroll
  for (int j = 0; j < 16; ++j) s[j] = 0.f;

  // stage t = 0
  {
    const size_t off = base0;
    bk[0][tid] = k[off + tid];
    bq[0][tid] = q[off + tid];
    if (tid < 16) bv[0][tid] = v[off + vc * 16 + tid];
    if (tid == 64) bs[0][0] = g[sbase0];
    if (tid == 65) bs[0][1] = beta[sbase0];
    if (tid == 66) bs[0][2] = sq[sbase0];
    if (tid == 67) bs[0][3] = sk[sbase0];
  }
  __syncthreads();

  const size_t obase = base0 + vc * 16 + c;

  for (int t = 0; t < T_; ++t) {
    const int cur = t & 1;
    const int nxt = cur ^ 1;
    if (t + 1 < T_) {
      const size_t off = base0 + (size_t)(t + 1) * tstride;
      bk[nxt][tid] = k[off + tid];
      bq[nxt][tid] = q[off + tid];
      if (tid < 16) bv[nxt][tid] = v[off + vc * 16 + tid];
      if (tid == 64) bs[nxt][0] = g[sbase0 + (size_t)(t + 1) * H_];
      if (tid == 65) bs[nxt][1] = beta[sbase0 + (size_t)(t + 1) * H_];
      if (tid == 66) bs[nxt][2] = sq[sbase0 + (size_t)(t + 1) * H_];
      if (tid == 67) bs[nxt][3] = sk[sbase0 + (size_t)(t + 1) * H_];
    }

    const float eg = __expf(bs[cur][0]);
    const float bb = bs[cur][1];
    const float qs = bs[cur][2];
    const float ks = bs[cur][3];

    float kj[16];
    float p = 0.f;
#pragma unroll
    for (int j = 0; j < 16; ++j) {
      kj[j] = bk[cur][16 * j + r] * ks;
      s[j] *= eg;
      p = fmaf(kj[j], s[j], p);
    }
    p += __shfl_xor(p, 1);
    p += __shfl_xor(p, 2);
    p += __shfl_xor(p, 4);
    p += __shfl_xor(p, 8);

    const float delta = (bv[cur][c] - p) * bb;

    float o = 0.f;
#pragma unroll
    for (int j = 0; j < 16; ++j) {
      s[j] = fmaf(kj[j], delta, s[j]);
      o = fmaf(bq[cur][16 * j + r], s[j], o);
    }
    o += __shfl_xor(o, 1);
    o += __shfl_xor(o, 2);
    o += __shfl_xor(o, 4);
    o += __shfl_xor(o, 8);

    if (r == 0) o_raw[obase + (size_t)t * tstride] = o * qs;
    __syncthreads();
  }
}

// ---------------------------------------------------------------------------
// Kernel 4: RMSNorm * norm_w * swish(gate), then per-head GroupLinear
//   out[bt, h*DK + d] = sum_v o_n[bt,h,v] * o_w[h,v,d]
// Block: (tile of 16 bt-values, h); 256 threads, thread owns output dim d.
// ---------------------------------------------------------------------------
__global__ __launch_bounds__(256) void gdn_out_kernel(
    const float* __restrict__ o_raw, const float* __restrict__ sgate,
    const float* __restrict__ norm_w, const float* __restrict__ o_w,
    float* __restrict__ out) {
  const int tile = blockIdx.x;
  const int h = blockIdx.y;
  const int tid = threadIdx.x;
  const int lane = tid & 63;
  const int wid = tid >> 6;

  __shared__ float on[16][DV_];
  __shared__ float red[16][4];
  __shared__ float rms_s[16];
  __shared__ float sgs_s[16];

  float x[16];
#pragma unroll
  for (int tt = 0; tt < 16; ++tt) {
    x[tt] = o_raw[((size_t)(tile * 16 + tt) * H_ + h) * DV_ + tid];
  }

#pragma unroll
  for (int tt = 0; tt < 16; ++tt) {
    float ssv = x[tt] * x[tt];
    ssv += __shfl_xor(ssv, 1);
    ssv += __shfl_xor(ssv, 2);
    ssv += __shfl_xor(ssv, 4);
    ssv += __shfl_xor(ssv, 8);
    ssv += __shfl_xor(ssv, 16);
    ssv += __shfl_xor(ssv, 32);
    if (lane == 0) red[tt][wid] = ssv;
  }
  __syncthreads();
  if (tid < 16) {
    const float ms =
        (red[tid][0] + red[tid][1] + red[tid][2] + red[tid][3]) * (1.f / DV_);
    rms_s[tid] = rsqrtf(ms + 1e-5f);
    sgs_s[tid] = sgate[(size_t)(tile * 16 + tid) * H_ + h];
  }
  __syncthreads();

  const float nw = norm_w[tid];
#pragma unroll
  for (int tt = 0; tt < 16; ++tt) {
    on[tt][tid] = x[tt] * rms_s[tt] * nw * sgs_s[tt];
  }
  __syncthreads();

  float acc[16];
#pragma unroll
  for (int tt = 0; tt < 16; ++tt) acc[tt] = 0.f;

  const float* wp = o_w + (size_t)h * DV_ * DK_ + tid;  // column d = tid
  for (int v4 = 0; v4 < DV_ / 4; ++v4) {
    const float w0 = wp[(4 * v4 + 0) * DK_];
    const float w1 = wp[(4 * v4 + 1) * DK_];
    const float w2 = wp[(4 * v4 + 2) * DK_];
    const float w3 = wp[(4 * v4 + 3) * DK_];
#pragma unroll
    for (int tt = 0; tt < 16; ++tt) {
      const float4 ov = *(const float4*)&on[tt][4 * v4];
      acc[tt] = fmaf(ov.x, w0,
                fmaf(ov.y, w1, fmaf(ov.z, w2, fmaf(ov.w, w3, acc[tt]))));
    }
  }

#pragma unroll
  for (int tt = 0; tt < 16; ++tt) {
    out[((size_t)(tile * 16 + tt) * H_ + h) * DK_ + tid] = acc[tt];
  }
}

// ---------------------------------------------------------------------------
extern "C" void kernel_launch(void* const* d_in, const int* in_sizes, int n_in,
                              void* d_out, int out_size, void* d_ws,
                              size_t ws_size, hipStream_t stream) {
  const float* hab = (const float*)d_in[0];
  const float* hg = (const float*)d_in[1];
  const float* q = (const float*)d_in[2];
  const float* k = (const float*)d_in[3];
  const float* v = (const float*)d_in[4];
  const float* b_w = (const float*)d_in[5];
  const float* a_w = (const float*)d_in[6];
  const float* A_log = (const float*)d_in[7];
  const float* dt_bias = (const float*)d_in[8];
  const float* g_w = (const float*)d_in[9];
  const float* norm_w = (const float*)d_in[10];
  const float* o_w = (const float*)d_in[11];
  float* out = (float*)d_out;

  float* ws = (float*)d_ws;
  const size_t NBT = (size_t)B_ * T_ * H_;  // 24576
  float* w_beta = ws;
  float* w_g = ws + NBT;
  float* w_sg = ws + 2 * NBT;
  float* w_sq = ws + 3 * NBT;
  float* w_sk = ws + 4 * NBT;
  float* w_o = ws + 5 * NBT;  // B*T*H*DV floats

  hipLaunchKernelGGL(gdn_proj_kernel, dim3(B_ * T_), dim3(256), 0, stream,
                     hab, hg, b_w, a_w, g_w, A_log, dt_bias, w_beta, w_g,
                     w_sg);
  hipLaunchKernelGGL(gdn_norm_kernel, dim3(B_ * T_ * H_ / 4), dim3(256), 0,
                     stream, q, k, w_sq, w_sk);
  hipLaunchKernelGGL(gdn_scan_kernel, dim3(B_ * H_ * 16), dim3(256), 0, stream,
                     q, k, v, w_beta, w_g, w_sq, w_sk, w_o);
  hipLaunchKernelGGL(gdn_out_kernel, dim3(B_ * T_ / 16, H_), dim3(256), 0,
                     stream, w_o, w_sg, norm_w, o_w, out);
}

// Round 2
// 1739.426 us; speedup vs baseline: 1.3996x; 1.3996x over previous
//
#include <hip/hip_runtime.h>
#include <hip/hip_bf16.h>
#include <math.h>

#define B_ 2
#define T_ 2048
#define H_ 6
#define DK_ 256
#define DV_ 256
#define HID_ 2048
#define C_ 64
#define NC_ 32

// ---------------------------------------------------------------------------
// Kernel 1: fused projections (unchanged from R1)
// ---------------------------------------------------------------------------
__global__ __launch_bounds__(256) void gdn_proj_kernel(
    const float* __restrict__ hab, const float* __restrict__ hg,
    const float* __restrict__ b_w, const float* __restrict__ a_w,
    const float* __restrict__ g_w, const float* __restrict__ A_log,
    const float* __restrict__ dt_bias,
    float* __restrict__ beta_o, float* __restrict__ g_o,
    float* __restrict__ sgate_o) {
  const int bt = blockIdx.x;
  const int tid = threadIdx.x;
  const int lane = tid & 63;
  const int wid = tid >> 6;

  const float* h1 = hab + (size_t)bt * HID_ + tid * 8;
  const float* h2 = hg + (size_t)bt * HID_ + tid * 8;
  const float4 xa = *(const float4*)(h1);
  const float4 xb = *(const float4*)(h1 + 4);
  const float4 ya = *(const float4*)(h2);
  const float4 yb = *(const float4*)(h2 + 4);

  float part[18];
#pragma unroll
  for (int n = 0; n < 6; ++n) {
    const float* wp = b_w + n * HID_ + tid * 8;
    const float4 w0 = *(const float4*)(wp);
    const float4 w1 = *(const float4*)(wp + 4);
    part[n] = xa.x * w0.x + xa.y * w0.y + xa.z * w0.z + xa.w * w0.w +
              xb.x * w1.x + xb.y * w1.y + xb.z * w1.z + xb.w * w1.w;
  }
#pragma unroll
  for (int n = 0; n < 6; ++n) {
    const float* wp = a_w + n * HID_ + tid * 8;
    const float4 w0 = *(const float4*)(wp);
    const float4 w1 = *(const float4*)(wp + 4);
    part[6 + n] = xa.x * w0.x + xa.y * w0.y + xa.z * w0.z + xa.w * w0.w +
                  xb.x * w1.x + xb.y * w1.y + xb.z * w1.z + xb.w * w1.w;
  }
#pragma unroll
  for (int n = 0; n < 6; ++n) {
    const float* wp = g_w + n * HID_ + tid * 8;
    const float4 w0 = *(const float4*)(wp);
    const float4 w1 = *(const float4*)(wp + 4);
    part[12 + n] = ya.x * w0.x + ya.y * w0.y + ya.z * w0.z + ya.w * w0.w +
                   yb.x * w1.x + yb.y * w1.y + yb.z * w1.z + yb.w * w1.w;
  }

  __shared__ float red[18][4];
#pragma unroll
  for (int i = 0; i < 18; ++i) {
    float x = part[i];
    x += __shfl_xor(x, 1);
    x += __shfl_xor(x, 2);
    x += __shfl_xor(x, 4);
    x += __shfl_xor(x, 8);
    x += __shfl_xor(x, 16);
    x += __shfl_xor(x, 32);
    if (lane == 0) red[i][wid] = x;
  }
  __syncthreads();

  if (tid < 18) {
    const float s = red[tid][0] + red[tid][1] + red[tid][2] + red[tid][3];
    if (tid < 6) {
      beta_o[(size_t)bt * H_ + tid] = 1.f / (1.f + __expf(-s));
    } else if (tid < 12) {
      const int n = tid - 6;
      const float x = s + dt_bias[n];
      const float sp = (x > 20.f) ? x : log1pf(__expf(x));
      g_o[(size_t)bt * H_ + n] = -__expf(A_log[n]) * sp;
    } else {
      const int n = tid - 12;
      sgate_o[(size_t)bt * H_ + n] = s / (1.f + __expf(-s));
    }
  }
}

// ---------------------------------------------------------------------------
// Kernel 2: q/k inverse L2 norms (unchanged from R1)
// ---------------------------------------------------------------------------
__global__ __launch_bounds__(256) void gdn_norm_kernel(
    const float* __restrict__ q, const float* __restrict__ k,
    float* __restrict__ sq, float* __restrict__ sk) {
  const int gw = blockIdx.x * 4 + (threadIdx.x >> 6);
  const int lane = threadIdx.x & 63;

  const float4 qv = *(const float4*)(q + (size_t)gw * DK_ + lane * 4);
  const float4 kv = *(const float4*)(k + (size_t)gw * DK_ + lane * 4);
  float sums_q = qv.x * qv.x + qv.y * qv.y + qv.z * qv.z + qv.w * qv.w;
  float sums_k = kv.x * kv.x + kv.y * kv.y + kv.z * kv.z + kv.w * kv.w;
#pragma unroll
  for (int m = 1; m < 64; m <<= 1) {
    sums_q += __shfl_xor(sums_q, m);
    sums_k += __shfl_xor(sums_k, m);
  }
  if (lane == 0) {
    sq[gw] = rsqrtf(sums_q + 1e-6f) * 0.0625f;
    sk[gw] = rsqrtf(sums_k + 1e-6f);
  }
}

// ---------------------------------------------------------------------------
// Kernel 3: per-chunk inclusive cumsum of g
// ---------------------------------------------------------------------------
__global__ __launch_bounds__(256) void gdn_cum_kernel(
    const float* __restrict__ g, float* __restrict__ Gc) {
  const int bh = blockIdx.x;
  const int b = bh / H_, h = bh - b * H_;
  const int w = threadIdx.x >> 6, l = threadIdx.x & 63;
  for (int it = 0; it < 8; ++it) {
    const int nc = it * 4 + w;
    const int tg = nc * C_ + l;
    float val = g[((size_t)b * T_ + tg) * H_ + h];
#pragma unroll
    for (int ofs = 1; ofs < 64; ofs <<= 1) {
      const float o = __shfl_up(val, ofs);
      if (l >= ofs) val += o;
    }
    Gc[(bh * NC_ + nc) * C_ + l] = val;
  }
}

// LDS XOR swizzle (16B-block granularity) for the [64][256] chunk tiles.
__device__ __forceinline__ int swz4(int row, int c4) {
  return row * 256 + (((c4) ^ ((row >> 2) & 7)) << 2);
}
__device__ __forceinline__ int swzi(int row, int c) {
  return row * 256 + ((((c) >> 2) ^ ((row >> 2) & 7)) << 2) + ((c) & 3);
}

// ---------------------------------------------------------------------------
// Kernel 4 (parallel over (b,h,chunk)): build A = tril(beta*expdG*K K^T),
// M = tril_incl(expdG * Q K^T) -> ws; forward-substitute (I+A)^{-1} on
// [beta*V | beta*Lam*K] to produce U, W -> ws.
// ---------------------------------------------------------------------------
__global__ __launch_bounds__(256) void gdn_prep_kernel(
    const float* __restrict__ q, const float* __restrict__ k,
    const float* __restrict__ v, const float* __restrict__ beta,
    const float* __restrict__ sq, const float* __restrict__ sk,
    const float* __restrict__ Gc, float* __restrict__ wU,
    float* __restrict__ wW, float* __restrict__ wM) {
  const int bid = blockIdx.x;
  const int bh = bid / NC_;
  const int nc = bid - bh * NC_;
  const int b = bh / H_, h = bh - b * H_;
  const int tid = threadIdx.x;
  const int w = tid >> 6, l = tid & 63;

  __shared__ float kl[C_ * 256];
  __shared__ float xb[C_ * 256];
  __shared__ float AlT[C_][68];  // AlT[i][t] = A[t][i]
  __shared__ float bG[C_], bB[C_];

  const size_t srow0 = ((size_t)b * T_ + nc * C_) * H_ + h;
  if (tid < C_) {
    bG[tid] = Gc[(bh * NC_ + nc) * C_ + tid];
    bB[tid] = beta[srow0 + (size_t)tid * H_];
  }
  // stage kn = k*sk, qn = q*sq
#pragma unroll
  for (int rr = 0; rr < 16; ++rr) {
    const int row = rr * 4 + w;
    const size_t g0 = (srow0 + (size_t)row * H_) * DK_;
    const float skr = sk[srow0 + (size_t)row * H_];
    const float sqr = sq[srow0 + (size_t)row * H_];
    float4 kv = *(const float4*)(k + g0 + 4 * l);
    float4 qv = *(const float4*)(q + g0 + 4 * l);
    kv.x *= skr; kv.y *= skr; kv.z *= skr; kv.w *= skr;
    qv.x *= sqr; qv.y *= sqr; qv.z *= sqr; qv.w *= sqr;
    *(float4*)&kl[swz4(row, l)] = kv;
    *(float4*)&xb[swz4(row, l)] = qv;
  }
  __syncthreads();

  const int R = tid >> 4, Cc = tid & 15;
  // ---- M = masked(exp(Gt-Gi) * qn kn^T), i <= t
  {
    float acc[4][4];
#pragma unroll
    for (int a = 0; a < 4; ++a)
#pragma unroll
      for (int b2 = 0; b2 < 4; ++b2) acc[a][b2] = 0.f;
    for (int k4 = 0; k4 < 64; ++k4) {
      float4 qr[4], kr4[4];
#pragma unroll
      for (int a = 0; a < 4; ++a) qr[a] = *(float4*)&xb[swz4(4 * R + a, k4)];
#pragma unroll
      for (int b2 = 0; b2 < 4; ++b2)
        kr4[b2] = *(float4*)&kl[swz4(4 * Cc + b2, k4)];
#pragma unroll
      for (int a = 0; a < 4; ++a)
#pragma unroll
        for (int b2 = 0; b2 < 4; ++b2)
          acc[a][b2] += qr[a].x * kr4[b2].x + qr[a].y * kr4[b2].y +
                        qr[a].z * kr4[b2].z + qr[a].w * kr4[b2].w;
    }
    float* mbase = wM + (size_t)(bh * NC_ + nc) * C_ * C_;
#pragma unroll
    for (int a = 0; a < 4; ++a) {
      const int t = 4 * R + a;
      float tmp[4];
#pragma unroll
      for (int b2 = 0; b2 < 4; ++b2) {
        const int i = 4 * Cc + b2;
        tmp[b2] = (i <= t) ? acc[a][b2] * __expf(bG[t] - bG[i]) : 0.f;
      }
      float4 ov; ov.x = tmp[0]; ov.y = tmp[1]; ov.z = tmp[2]; ov.w = tmp[3];
      *(float4*)&mbase[t * C_ + 4 * Cc] = ov;
    }
  }
  // ---- A (strictly lower), stored transposed
  if (Cc <= R) {
    float acc[4][4];
#pragma unroll
    for (int a = 0; a < 4; ++a)
#pragma unroll
      for (int b2 = 0; b2 < 4; ++b2) acc[a][b2] = 0.f;
    for (int k4 = 0; k4 < 64; ++k4) {
      float4 ar[4], br4[4];
#pragma unroll
      for (int a = 0; a < 4; ++a) ar[a] = *(float4*)&kl[swz4(4 * R + a, k4)];
#pragma unroll
      for (int b2 = 0; b2 < 4; ++b2)
        br4[b2] = *(float4*)&kl[swz4(4 * Cc + b2, k4)];
#pragma unroll
      for (int a = 0; a < 4; ++a)
#pragma unroll
        for (int b2 = 0; b2 < 4; ++b2)
          acc[a][b2] += ar[a].x * br4[b2].x + ar[a].y * br4[b2].y +
                        ar[a].z * br4[b2].z + ar[a].w * br4[b2].w;
    }
#pragma unroll
    for (int a = 0; a < 4; ++a) {
      const int t = 4 * R + a;
#pragma unroll
      for (int b2 = 0; b2 < 4; ++b2) {
        const int i = 4 * Cc + b2;
        AlT[i][t] = (i < t) ? bB[t] * __expf(bG[t] - bG[i]) * acc[a][b2] : 0.f;
      }
    }
  }
  __syncthreads();
  // scale kl in place by beta*Lambda; stage beta*V into xb (over qn)
#pragma unroll
  for (int rr = 0; rr < 16; ++rr) {
    const int row = rr * 4 + w;
    const float bbr = bB[row];
    const float sc = bbr * __expf(bG[row]);
    float4 kv = *(float4*)&kl[swz4(row, l)];
    kv.x *= sc; kv.y *= sc; kv.z *= sc; kv.w *= sc;
    *(float4*)&kl[swz4(row, l)] = kv;
    const size_t g0 = (srow0 + (size_t)row * H_) * DV_;
    float4 vv = *(const float4*)(v + g0 + 4 * l);
    vv.x *= bbr; vv.y *= bbr; vv.z *= bbr; vv.w *= bbr;
    *(float4*)&xb[swz4(row, l)] = vv;
  }
  __syncthreads();
  // ---- forward substitution, column tid on both RHS (column-private, no bar)
#pragma unroll
  for (int tb = 0; tb < 8; ++tb) {
    float xu[8], xw[8];
#pragma unroll
    for (int e = 0; e < 8; ++e) {
      xu[e] = xb[swzi(8 * tb + e, tid)];
      xw[e] = kl[swzi(8 * tb + e, tid)];
    }
    for (int i = 0; i < 8 * tb; ++i) {
      const float xui = xb[swzi(i, tid)];
      const float xwi = kl[swzi(i, tid)];
      float av[8];
      *(float4*)&av[0] = *(float4*)&AlT[i][8 * tb];
      *(float4*)&av[4] = *(float4*)&AlT[i][8 * tb + 4];
#pragma unroll
      for (int e = 0; e < 8; ++e) {
        xu[e] = fmaf(-av[e], xui, xu[e]);
        xw[e] = fmaf(-av[e], xwi, xw[e]);
      }
    }
#pragma unroll
    for (int e = 1; e < 8; ++e)
#pragma unroll
      for (int m = 0; m < 7; ++m)
        if (m < e) {
          const float am = AlT[8 * tb + m][8 * tb + e];
          xu[e] = fmaf(-am, xu[m], xu[e]);
          xw[e] = fmaf(-am, xw[m], xw[e]);
        }
#pragma unroll
    for (int e = 0; e < 8; ++e) {
      xb[swzi(8 * tb + e, tid)] = xu[e];
      kl[swzi(8 * tb + e, tid)] = xw[e];
    }
  }
  // ---- store U, W
  {
    float* ub = wU + (size_t)(bh * NC_ + nc) * C_ * 256;
    float* wb = wW + (size_t)(bh * NC_ + nc) * C_ * 256;
    for (int row = 0; row < C_; ++row) {
      ub[row * 256 + tid] = xb[swzi(row, tid)];
      wb[row * 256 + tid] = kl[swzi(row, tid)];
    }
  }
}

// ---------------------------------------------------------------------------
// Kernel 5 (sequential over chunks): per (b,h,colblock of 16 v-cols) carry
// S[256][16] in registers. Per chunk: delta = U - W*S ; o_part = Lam*(Q*S);
// S = LamC*S + Kd^T * delta. 3-phase LDS double-buffer, loads issued early.
// ---------------------------------------------------------------------------
__global__ __launch_bounds__(256) void gdn_seq_kernel(
    const float* __restrict__ q, const float* __restrict__ k,
    const float* __restrict__ sq, const float* __restrict__ sk,
    const float* __restrict__ Gc, const float* __restrict__ wU,
    const float* __restrict__ wW, float* __restrict__ wDelta,
    float* __restrict__ o_raw) {
  const int bid = blockIdx.x;
  const int bh = bid >> 4, cb = bid & 15;
  const int b = bh / H_, h = bh - b * H_;
  const int tid = threadIdx.x;
  const int kr = tid & 15, cl = tid >> 4;
  const int c = cb * 16 + cl;
  const int w = tid >> 6, l = tid & 63;

  __shared__ float ob[2][C_ * 260];
  __shared__ float Ul[2][C_ * 20];
  __shared__ float dl[C_ * 17];
  __shared__ float bGd[2][C_];

  float s[16];
#pragma unroll
  for (int j = 0; j < 16; ++j) s[j] = 0.f;

  // prologue: stage W(0), Ul(0), G(0) into parity 0
  {
    const float* wb = wW + (size_t)(bh * NC_) * C_ * 256;
#pragma unroll
    for (int rr = 0; rr < 16; ++rr) {
      const int row = rr * 4 + w;
      *(float4*)&ob[0][row * 260 + 4 * l] =
          *(const float4*)(wb + row * 256 + 4 * l);
    }
    const int t = tid >> 2, cp = tid & 3;
    *(float4*)&Ul[0][t * 20 + 4 * cp] = *(const float4*)(
        wU + ((size_t)(bh * NC_) * C_ + t) * 256 + cb * 16 + 4 * cp);
    if (tid < C_) bGd[0][tid] = Gc[(bh * NC_) * C_ + tid];
  }
  __syncthreads();

  for (int nc = 0; nc < NC_; ++nc) {
    const int pw = nc & 1;
    const size_t rowg0 = ((size_t)b * T_ + nc * C_) * H_ + h;
    float4 st[16];
    // ==== P1: issue Q loads; GEMM1 delta = U - W*S; write Q; barrier
#pragma unroll
    for (int rr = 0; rr < 16; ++rr) {
      const int row = rr * 4 + w;
      st[rr] = *(const float4*)(q + (rowg0 + (size_t)row * H_) * DK_ + 4 * l);
    }
    {
      const float* wbuf = &ob[pw][0];
      const float* Ub = &Ul[pw][0];
      float* dW = wDelta + (size_t)(bh * NC_ + nc) * C_ * 256;
      for (int t = 0; t < C_; ++t) {
        const float* wrow = wbuf + t * 260;
        float p0 = wrow[kr] * s[0];
        float p1 = wrow[16 + kr] * s[1];
        float p2 = wrow[32 + kr] * s[2];
        float p3 = wrow[48 + kr] * s[3];
#pragma unroll
        for (int j = 4; j < 16; j += 4) {
          p0 = fmaf(wrow[16 * j + kr], s[j], p0);
          p1 = fmaf(wrow[16 * (j + 1) + kr], s[j + 1], p1);
          p2 = fmaf(wrow[16 * (j + 2) + kr], s[j + 2], p2);
          p3 = fmaf(wrow[16 * (j + 3) + kr], s[j + 3], p3);
        }
        float p = (p0 + p1) + (p2 + p3);
        p += __shfl_xor(p, 1);
        p += __shfl_xor(p, 2);
        p += __shfl_xor(p, 4);
        p += __shfl_xor(p, 8);
        const float del = Ub[t * 20 + cl] - p;
        if (kr == 0) {
          dl[t * 17 + cl] = del;
          dW[t * 256 + c] = del;
        }
      }
    }
#pragma unroll
    for (int rr = 0; rr < 16; ++rr) {
      const int row = rr * 4 + w;
      const float sc = sq[rowg0 + (size_t)row * H_];
      float4 vv = st[rr];
      vv.x *= sc; vv.y *= sc; vv.z *= sc; vv.w *= sc;
      *(float4*)&ob[pw ^ 1][row * 260 + 4 * l] = vv;
    }
    __syncthreads();

    // ==== P2: issue K loads; GEMM3 o_part = Lam*(Q*S); write Kd; barrier
#pragma unroll
    for (int rr = 0; rr < 16; ++rr) {
      const int row = rr * 4 + w;
      st[rr] = *(const float4*)(k + (rowg0 + (size_t)row * H_) * DK_ + 4 * l);
    }
    {
      const float* qbuf = &ob[pw ^ 1][0];
      for (int t = 0; t < C_; ++t) {
        const float* qrow = qbuf + t * 260;
        float p0 = qrow[kr] * s[0];
        float p1 = qrow[16 + kr] * s[1];
        float p2 = qrow[32 + kr] * s[2];
        float p3 = qrow[48 + kr] * s[3];
#pragma unroll
        for (int j = 4; j < 16; j += 4) {
          p0 = fmaf(qrow[16 * j + kr], s[j], p0);
          p1 = fmaf(qrow[16 * (j + 1) + kr], s[j + 1], p1);
          p2 = fmaf(qrow[16 * (j + 2) + kr], s[j + 2], p2);
          p3 = fmaf(qrow[16 * (j + 3) + kr], s[j + 3], p3);
        }
        float p = (p0 + p1) + (p2 + p3);
        p += __shfl_xor(p, 1);
        p += __shfl_xor(p, 2);
        p += __shfl_xor(p, 4);
        p += __shfl_xor(p, 8);
        if (kr == 0)
          o_raw[(rowg0 + (size_t)t * H_) * DV_ + c] = __expf(bGd[pw][t]) * p;
      }
    }
    const float gend = bGd[pw][C_ - 1];
#pragma unroll
    for (int rr = 0; rr < 16; ++rr) {
      const int row = rr * 4 + w;
      const float sc = __expf(gend - bGd[pw][row]) * sk[rowg0 + (size_t)row * H_];
      float4 vv = st[rr];
      vv.x *= sc; vv.y *= sc; vv.z *= sc; vv.w *= sc;
      *(float4*)&ob[pw][row * 260 + 4 * l] = vv;
    }
    __syncthreads();

    // ==== P3: issue W(nc+1)/Ul/G loads; GEMM2 S = LamC*S + Kd^T delta; barrier
    const bool more = (nc + 1 < NC_);
    float4 uld;
    float gnext = 0.f;
    if (more) {
#pragma unroll
      for (int rr = 0; rr < 16; ++rr) {
        const int row = rr * 4 + w;
        st[rr] = *(const float4*)(
            wW + ((size_t)(bh * NC_ + nc + 1) * C_ + row) * 256 + 4 * l);
      }
      const int t = tid >> 2, cp = tid & 3;
      uld = *(const float4*)(
          wU + ((size_t)(bh * NC_ + nc + 1) * C_ + t) * 256 + cb * 16 + 4 * cp);
      if (tid < C_) gnext = Gc[(bh * NC_ + nc + 1) * C_ + tid];
    }
    {
      const float lamC = __expf(gend);
#pragma unroll
      for (int j = 0; j < 16; ++j) s[j] *= lamC;
      const float* kbuf = &ob[pw][0];
      for (int t = 0; t < C_; ++t) {
        const float dv = dl[t * 17 + cl];
        const float* krow = kbuf + t * 260;
#pragma unroll
        for (int j = 0; j < 16; ++j)
          s[j] = fmaf(krow[16 * j + kr], dv, s[j]);
      }
    }
    if (more) {
#pragma unroll
      for (int rr = 0; rr < 16; ++rr) {
        const int row = rr * 4 + w;
        *(float4*)&ob[pw ^ 1][row * 260 + 4 * l] = st[rr];
      }
      const int t = tid >> 2, cp = tid & 3;
      *(float4*)&Ul[pw ^ 1][t * 20 + 4 * cp] = uld;
      if (tid < C_) bGd[pw ^ 1][tid] = gnext;
    }
    __syncthreads();
  }
}

// ---------------------------------------------------------------------------
// Kernel 6 (parallel): o_raw += M * delta  per (b,h,chunk)
// ---------------------------------------------------------------------------
__global__ __launch_bounds__(256) void gdn_outadd_kernel(
    const float* __restrict__ wM, const float* __restrict__ wDelta,
    float* __restrict__ o_raw) {
  const int bid = blockIdx.x;
  const int bh = bid / NC_;
  const int nc = bid - bh * NC_;
  const int b = bh / H_, h = bh - b * H_;
  const int tid = threadIdx.x;
  const int w = tid >> 6, l = tid & 63;
  __shared__ float Ml[C_ * C_];
  __shared__ float dl2[C_ * 260];
  const float* mb = wM + (size_t)(bh * NC_ + nc) * C_ * C_;
  for (int idx = tid; idx < C_ * C_; idx += 256) Ml[idx] = mb[idx];
  const float* db = wDelta + (size_t)(bh * NC_ + nc) * C_ * 256;
#pragma unroll
  for (int rr = 0; rr < 16; ++rr) {
    const int row = rr * 4 + w;
    *(float4*)&dl2[row * 260 + 4 * l] = *(const float4*)(db + row * 256 + 4 * l);
  }
  __syncthreads();
  const size_t rowg0 = ((size_t)b * T_ + nc * C_) * H_ + h;
  for (int t = 0; t < C_; ++t) {
    const float* mrow = Ml + t * C_;
    float a0 = 0.f, a1 = 0.f, a2 = 0.f, a3 = 0.f;
    int i = 0;
    for (; i + 4 <= t + 1; i += 4) {
      a0 = fmaf(mrow[i], dl2[i * 260 + tid], a0);
      a1 = fmaf(mrow[i + 1], dl2[(i + 1) * 260 + tid], a1);
      a2 = fmaf(mrow[i + 2], dl2[(i + 2) * 260 + tid], a2);
      a3 = fmaf(mrow[i + 3], dl2[(i + 3) * 260 + tid], a3);
    }
    for (; i <= t; ++i) a0 = fmaf(mrow[i], dl2[i * 260 + tid], a0);
    o_raw[(rowg0 + (size_t)t * H_) * DV_ + tid] += (a0 + a1) + (a2 + a3);
  }
}

// ---------------------------------------------------------------------------
// Kernel 7: RMSNorm * norm_w * swish(gate), per-head GroupLinear (unchanged)
// ---------------------------------------------------------------------------
__global__ __launch_bounds__(256) void gdn_out_kernel(
    const float* __restrict__ o_raw, const float* __restrict__ sgate,
    const float* __restrict__ norm_w, const float* __restrict__ o_w,
    float* __restrict__ out) {
  const int tile = blockIdx.x;
  const int h = blockIdx.y;
  const int tid = threadIdx.x;
  const int lane = tid & 63;
  const int wid = tid >> 6;

  __shared__ float on[16][DV_];
  __shared__ float red[16][4];
  __shared__ float rms_s[16];
  __shared__ float sgs_s[16];

  float x[16];
#pragma unroll
  for (int tt = 0; tt < 16; ++tt) {
    x[tt] = o_raw[((size_t)(tile * 16 + tt) * H_ + h) * DV_ + tid];
  }

#pragma unroll
  for (int tt = 0; tt < 16; ++tt) {
    float ssv = x[tt] * x[tt];
    ssv += __shfl_xor(ssv, 1);
    ssv += __shfl_xor(ssv, 2);
    ssv += __shfl_xor(ssv, 4);
    ssv += __shfl_xor(ssv, 8);
    ssv += __shfl_xor(ssv, 16);
    ssv += __shfl_xor(ssv, 32);
    if (lane == 0) red[tt][wid] = ssv;
  }
  __syncthreads();
  if (tid < 16) {
    const float ms =
        (red[tid][0] + red[tid][1] + red[tid][2] + red[tid][3]) * (1.f / DV_);
    rms_s[tid] = rsqrtf(ms + 1e-5f);
    sgs_s[tid] = sgate[(size_t)(tile * 16 + tid) * H_ + h];
  }
  __syncthreads();

  const float nw = norm_w[tid];
#pragma unroll
  for (int tt = 0; tt < 16; ++tt) {
    on[tt][tid] = x[tt] * rms_s[tt] * nw * sgs_s[tt];
  }
  __syncthreads();

  float acc[16];
#pragma unroll
  for (int tt = 0; tt < 16; ++tt) acc[tt] = 0.f;

  const float* wp = o_w + (size_t)h * DV_ * DK_ + tid;
  for (int v4 = 0; v4 < DV_ / 4; ++v4) {
    const float w0 = wp[(4 * v4 + 0) * DK_];
    const float w1 = wp[(4 * v4 + 1) * DK_];
    const float w2 = wp[(4 * v4 + 2) * DK_];
    const float w3 = wp[(4 * v4 + 3) * DK_];
#pragma unroll
    for (int tt = 0; tt < 16; ++tt) {
      const float4 ov = *(const float4*)&on[tt][4 * v4];
      acc[tt] = fmaf(ov.x, w0,
                fmaf(ov.y, w1, fmaf(ov.z, w2, fmaf(ov.w, w3, acc[tt]))));
    }
  }

#pragma unroll
  for (int tt = 0; tt < 16; ++tt) {
    out[((size_t)(tile * 16 + tt) * H_ + h) * DK_ + tid] = acc[tt];
  }
}

// ---------------------------------------------------------------------------
extern "C" void kernel_launch(void* const* d_in, const int* in_sizes, int n_in,
                              void* d_out, int out_size, void* d_ws,
                              size_t ws_size, hipStream_t stream) {
  const float* hab = (const float*)d_in[0];
  const float* hg = (const float*)d_in[1];
  const float* q = (const float*)d_in[2];
  const float* k = (const float*)d_in[3];
  const float* v = (const float*)d_in[4];
  const float* b_w = (const float*)d_in[5];
  const float* a_w = (const float*)d_in[6];
  const float* A_log = (const float*)d_in[7];
  const float* dt_bias = (const float*)d_in[8];
  const float* g_w = (const float*)d_in[9];
  const float* norm_w = (const float*)d_in[10];
  const float* o_w = (const float*)d_in[11];
  float* out = (float*)d_out;

  float* ws = (float*)d_ws;
  const size_t NBT = (size_t)B_ * T_ * H_;          // 24576
  const size_t CHW = (size_t)B_ * H_ * NC_ * C_ * 256;  // 6291456
  float* w_beta = ws;
  float* w_g = ws + NBT;
  float* w_sg = ws + 2 * NBT;
  float* w_sq = ws + 3 * NBT;
  float* w_sk = ws + 4 * NBT;
  float* w_G = ws + 5 * NBT;                         // B*H*NC*C == NBT
  float* w_U = ws + 6 * NBT;
  float* w_W = w_U + CHW;
  float* w_M = w_W + CHW;
  float* w_delta = w_M + (size_t)B_ * H_ * NC_ * C_ * C_;
  float* w_o = w_delta + CHW;

  hipLaunchKernelGGL(gdn_proj_kernel, dim3(B_ * T_), dim3(256), 0, stream,
                     hab, hg, b_w, a_w, g_w, A_log, dt_bias, w_beta, w_g, w_sg);
  hipLaunchKernelGGL(gdn_norm_kernel, dim3(B_ * T_ * H_ / 4), dim3(256), 0,
                     stream, q, k, w_sq, w_sk);
  hipLaunchKernelGGL(gdn_cum_kernel, dim3(B_ * H_), dim3(256), 0, stream,
                     w_g, w_G);
  hipLaunchKernelGGL(gdn_prep_kernel, dim3(B_ * H_ * NC_), dim3(256), 0,
                     stream, q, k, v, w_beta, w_sq, w_sk, w_G, w_U, w_W, w_M);
  hipLaunchKernelGGL(gdn_seq_kernel, dim3(B_ * H_ * 16), dim3(256), 0, stream,
                     q, k, w_sq, w_sk, w_G, w_U, w_W, w_delta, w_o);
  hipLaunchKernelGGL(gdn_outadd_kernel, dim3(B_ * H_ * NC_), dim3(256), 0,
                     stream, w_M, w_delta, w_o);
  hipLaunchKernelGGL(gdn_out_kernel, dim3(B_ * T_ / 16, H_), dim3(256), 0,
                     stream, w_o, w_sg, norm_w, o_w, out);
}

// Round 3
// 874.038 us; speedup vs baseline: 2.7854x; 1.9901x over previous
//
#include <hip/hip_runtime.h>
#include <hip/hip_bf16.h>
#include <math.h>

#define B_ 2
#define T_ 2048
#define H_ 6
#define DK_ 256
#define DV_ 256
#define HID_ 2048
#define C_ 64
#define NC_ 32

typedef __attribute__((ext_vector_type(8))) short short8;
typedef __attribute__((ext_vector_type(4))) float f32x4;

__device__ __forceinline__ unsigned rnebf(float f) {
  unsigned u = __float_as_uint(f);
  return (u + 0x7fffu + ((u >> 16) & 1u)) >> 16;
}
__device__ __forceinline__ unsigned pkbf(float lo, float hi) {
  return rnebf(lo) | (rnebf(hi) << 16);
}
__device__ __forceinline__ float bf2f(unsigned u16v) {
  return __uint_as_float((u16v & 0xffffu) << 16);
}
__device__ __forceinline__ short8 u4_to_s8(uint4 u) {
  union { uint4 u; short8 s; } c; c.u = u; return c.s;
}

// Build MFMA B-fragment (16x16x32 bf16) for k-tile from two C/D-layout packed
// mtiles Pe (even, rows 32kt..32kt+15) and Po (odd, rows +16..+31).
// C/D: (col=l&15, row=16m+4*(l>>4)+r). B: (col=l&15, k=32kt+8*(l>>4)+j).
__device__ __forceinline__ short8 buildB(uint2 Pe, uint2 Po, int lg, int c16) {
  const int src0 = ((2 * (lg & 1)) << 4) | c16;
  const int src1 = src0 + 16;
  int e0 = __shfl((int)Pe.x, src0), o0 = __shfl((int)Po.x, src0);
  int e1 = __shfl((int)Pe.y, src0), o1 = __shfl((int)Po.y, src0);
  int e2 = __shfl((int)Pe.x, src1), o2 = __shfl((int)Po.x, src1);
  int e3 = __shfl((int)Pe.y, src1), o3 = __shfl((int)Po.y, src1);
  const bool lo2 = (lg < 2);
  union { int i[4]; short8 s; } u;
  u.i[0] = lo2 ? e0 : o0;
  u.i[1] = lo2 ? e1 : o1;
  u.i[2] = lo2 ? e2 : o2;
  u.i[3] = lo2 ? e3 : o3;
  return u.s;
}

// ---------------------------------------------------------------------------
// Kernel 1: fused projections (unchanged)
// ---------------------------------------------------------------------------
__global__ __launch_bounds__(256) void gdn_proj_kernel(
    const float* __restrict__ hab, const float* __restrict__ hg,
    const float* __restrict__ b_w, const float* __restrict__ a_w,
    const float* __restrict__ g_w, const float* __restrict__ A_log,
    const float* __restrict__ dt_bias,
    float* __restrict__ beta_o, float* __restrict__ g_o,
    float* __restrict__ sgate_o) {
  const int bt = blockIdx.x;
  const int tid = threadIdx.x;
  const int lane = tid & 63;
  const int wid = tid >> 6;

  const float* h1 = hab + (size_t)bt * HID_ + tid * 8;
  const float* h2 = hg + (size_t)bt * HID_ + tid * 8;
  const float4 xa = *(const float4*)(h1);
  const float4 xb = *(const float4*)(h1 + 4);
  const float4 ya = *(const float4*)(h2);
  const float4 yb = *(const float4*)(h2 + 4);

  float part[18];
#pragma unroll
  for (int n = 0; n < 6; ++n) {
    const float* wp = b_w + n * HID_ + tid * 8;
    const float4 w0 = *(const float4*)(wp);
    const float4 w1 = *(const float4*)(wp + 4);
    part[n] = xa.x * w0.x + xa.y * w0.y + xa.z * w0.z + xa.w * w0.w +
              xb.x * w1.x + xb.y * w1.y + xb.z * w1.z + xb.w * w1.w;
  }
#pragma unroll
  for (int n = 0; n < 6; ++n) {
    const float* wp = a_w + n * HID_ + tid * 8;
    const float4 w0 = *(const float4*)(wp);
    const float4 w1 = *(const float4*)(wp + 4);
    part[6 + n] = xa.x * w0.x + xa.y * w0.y + xa.z * w0.z + xa.w * w0.w +
                  xb.x * w1.x + xb.y * w1.y + xb.z * w1.z + xb.w * w1.w;
  }
#pragma unroll
  for (int n = 0; n < 6; ++n) {
    const float* wp = g_w + n * HID_ + tid * 8;
    const float4 w0 = *(const float4*)(wp);
    const float4 w1 = *(const float4*)(wp + 4);
    part[12 + n] = ya.x * w0.x + ya.y * w0.y + ya.z * w0.z + ya.w * w0.w +
                   yb.x * w1.x + yb.y * w1.y + yb.z * w1.z + yb.w * w1.w;
  }

  __shared__ float red[18][4];
#pragma unroll
  for (int i = 0; i < 18; ++i) {
    float x = part[i];
    x += __shfl_xor(x, 1);
    x += __shfl_xor(x, 2);
    x += __shfl_xor(x, 4);
    x += __shfl_xor(x, 8);
    x += __shfl_xor(x, 16);
    x += __shfl_xor(x, 32);
    if (lane == 0) red[i][wid] = x;
  }
  __syncthreads();

  if (tid < 18) {
    const float s = red[tid][0] + red[tid][1] + red[tid][2] + red[tid][3];
    if (tid < 6) {
      beta_o[(size_t)bt * H_ + tid] = 1.f / (1.f + __expf(-s));
    } else if (tid < 12) {
      const int n = tid - 6;
      const float x = s + dt_bias[n];
      const float sp = (x > 20.f) ? x : log1pf(__expf(x));
      g_o[(size_t)bt * H_ + n] = -__expf(A_log[n]) * sp;
    } else {
      const int n = tid - 12;
      sgate_o[(size_t)bt * H_ + n] = s / (1.f + __expf(-s));
    }
  }
}

// ---------------------------------------------------------------------------
// Kernel 2: q/k inverse L2 norms (unchanged)
// ---------------------------------------------------------------------------
__global__ __launch_bounds__(256) void gdn_norm_kernel(
    const float* __restrict__ q, const float* __restrict__ k,
    float* __restrict__ sq, float* __restrict__ sk) {
  const int gw = blockIdx.x * 4 + (threadIdx.x >> 6);
  const int lane = threadIdx.x & 63;

  const float4 qv = *(const float4*)(q + (size_t)gw * DK_ + lane * 4);
  const float4 kv = *(const float4*)(k + (size_t)gw * DK_ + lane * 4);
  float sums_q = qv.x * qv.x + qv.y * qv.y + qv.z * qv.z + qv.w * qv.w;
  float sums_k = kv.x * kv.x + kv.y * kv.y + kv.z * kv.z + kv.w * kv.w;
#pragma unroll
  for (int m = 1; m < 64; m <<= 1) {
    sums_q += __shfl_xor(sums_q, m);
    sums_k += __shfl_xor(sums_k, m);
  }
  if (lane == 0) {
    sq[gw] = rsqrtf(sums_q + 1e-6f) * 0.0625f;
    sk[gw] = rsqrtf(sums_k + 1e-6f);
  }
}

// ---------------------------------------------------------------------------
// Kernel 3: per-chunk inclusive cumsum of g; also sqe = sq*exp(G)
// ---------------------------------------------------------------------------
__global__ __launch_bounds__(256) void gdn_cum_kernel(
    const float* __restrict__ g, const float* __restrict__ sq,
    float* __restrict__ Gc, float* __restrict__ sqe) {
  const int bh = blockIdx.x;
  const int b = bh / H_, h = bh - b * H_;
  const int w = threadIdx.x >> 6, l = threadIdx.x & 63;
  for (int it = 0; it < 8; ++it) {
    const int nc = it * 4 + w;
    const int tg = nc * C_ + l;
    const size_t srow = ((size_t)b * T_ + tg) * H_ + h;
    float val = g[srow];
#pragma unroll
    for (int ofs = 1; ofs < 64; ofs <<= 1) {
      const float o = __shfl_up(val, ofs);
      if (l >= ofs) val += o;
    }
    Gc[(bh * NC_ + nc) * C_ + l] = val;
    sqe[srow] = sq[srow] * __expf(val);
  }
}

// ---------------------------------------------------------------------------
// Kernel 3b: Qd = q * sqe  (bf16, row-major [B,T,H,DK])
// ---------------------------------------------------------------------------
__global__ __launch_bounds__(256) void gdn_qscale_kernel(
    const float* __restrict__ q, const float* __restrict__ sqe,
    ushort* __restrict__ wQd) {
  const size_t i8 = (size_t)blockIdx.x * 256 + threadIdx.x;
  const size_t i0 = i8 * 8;
  const float s = sqe[i8 >> 5];
  const float4 a = *(const float4*)(q + i0);
  const float4 b = *(const float4*)(q + i0 + 4);
  uint4 o;
  o.x = pkbf(a.x * s, a.y * s);
  o.y = pkbf(a.z * s, a.w * s);
  o.z = pkbf(b.x * s, b.y * s);
  o.w = pkbf(b.z * s, b.w * s);
  *(uint4*)&wQd[i0] = o;
}

// ---------------------------------------------------------------------------
// Kernel 3c: kT[bh][d][t] = k[t][d] * exp(gend - G[t]) * sk[t]  (bf16)
// One block per (bh, chunk).
// ---------------------------------------------------------------------------
__global__ __launch_bounds__(256) void gdn_ktrans_kernel(
    const float* __restrict__ k, const float* __restrict__ sk,
    const float* __restrict__ Gc, ushort* __restrict__ wkT) {
  const int bid = blockIdx.x;
  const int bh = bid / NC_, nc = bid - bh * NC_;
  const int b = bh / H_, h = bh - b * H_;
  const int tid = threadIdx.x;
  const int cidx = bh * NC_ + nc;
  const size_t srow0 = ((size_t)b * T_ + nc * C_) * H_ + h;

  __shared__ ushort ldsT[256 * 68];
  const float gend = Gc[cidx * C_ + C_ - 1];

#pragma unroll
  for (int p = 0; p < 4; ++p) {
    const int t = p * 16 + (tid >> 4);
    const float scale =
        __expf(gend - Gc[cidx * C_ + t]) * sk[srow0 + (size_t)t * H_];
#pragma unroll
    for (int s = 0; s < 4; ++s) {
      const int col = 64 * s + 4 * (tid & 15);
      const float4 kv = *(const float4*)(k + (srow0 + (size_t)t * H_) * DK_ + col);
      ldsT[(col + 0) * 68 + t] = (ushort)rnebf(kv.x * scale);
      ldsT[(col + 1) * 68 + t] = (ushort)rnebf(kv.y * scale);
      ldsT[(col + 2) * 68 + t] = (ushort)rnebf(kv.z * scale);
      ldsT[(col + 3) * 68 + t] = (ushort)rnebf(kv.w * scale);
    }
  }
  __syncthreads();

  const int e = tid & 7;
#pragma unroll
  for (int p = 0; p < 8; ++p) {
    const int d = p * 32 + (tid >> 3);
    uint2 lo = *(uint2*)&ldsT[d * 68 + 8 * e];
    uint2 hi = *(uint2*)&ldsT[d * 68 + 8 * e + 4];
    uint4 o; o.x = lo.x; o.y = lo.y; o.z = hi.x; o.w = hi.y;
    *(uint4*)&wkT[((size_t)bh * 256 + d) * T_ + nc * C_ + 8 * e] = o;
  }
}

// LDS XOR swizzle for prep tiles
__device__ __forceinline__ int swz4(int row, int c4) {
  return row * 256 + (((c4) ^ ((row >> 2) & 7)) << 2);
}
__device__ __forceinline__ int swzi(int row, int c) {
  return row * 256 + ((((c) >> 2) ^ ((row >> 2) & 7)) << 2) + ((c) & 3);
}

// ---------------------------------------------------------------------------
// Kernel 4 (parallel, per (b,h,chunk)): A, M, forward-substitution -> U, W.
// Stores: M bf16 row-major, W bf16 row-major, U bf16 C/D-fragment packed.
// ---------------------------------------------------------------------------
__global__ __launch_bounds__(256) void gdn_prep_kernel(
    const float* __restrict__ q, const float* __restrict__ k,
    const float* __restrict__ v, const float* __restrict__ beta,
    const float* __restrict__ sq, const float* __restrict__ sk,
    const float* __restrict__ Gc, uint2* __restrict__ wUp,
    ushort* __restrict__ wWp, ushort* __restrict__ wMp) {
  const int bid = blockIdx.x;
  const int bh = bid / NC_;
  const int nc = bid - bh * NC_;
  const int b = bh / H_, h = bh - b * H_;
  const int tid = threadIdx.x;
  const int w = tid >> 6, l = tid & 63;
  const int cidx = bh * NC_ + nc;

  __shared__ float kl[C_ * 256];
  __shared__ float xb[C_ * 256];
  __shared__ float AlT[C_][68];
  __shared__ float bG[C_], bB[C_];

  const size_t srow0 = ((size_t)b * T_ + nc * C_) * H_ + h;
  if (tid < C_) {
    bG[tid] = Gc[cidx * C_ + tid];
    bB[tid] = beta[srow0 + (size_t)tid * H_];
  }
#pragma unroll
  for (int rr = 0; rr < 16; ++rr) {
    const int row = rr * 4 + w;
    const size_t g0 = (srow0 + (size_t)row * H_) * DK_;
    const float skr = sk[srow0 + (size_t)row * H_];
    const float sqr = sq[srow0 + (size_t)row * H_];
    float4 kv = *(const float4*)(k + g0 + 4 * l);
    float4 qv = *(const float4*)(q + g0 + 4 * l);
    kv.x *= skr; kv.y *= skr; kv.z *= skr; kv.w *= skr;
    qv.x *= sqr; qv.y *= sqr; qv.z *= sqr; qv.w *= sqr;
    *(float4*)&kl[swz4(row, l)] = kv;
    *(float4*)&xb[swz4(row, l)] = qv;
  }
  __syncthreads();

  const int R = tid >> 4, Cc = tid & 15;
  // ---- M = masked(exp(Gt-Gi) * qn kn^T), i <= t  (bf16 row-major)
  {
    float acc[4][4];
#pragma unroll
    for (int a = 0; a < 4; ++a)
#pragma unroll
      for (int b2 = 0; b2 < 4; ++b2) acc[a][b2] = 0.f;
    for (int k4 = 0; k4 < 64; ++k4) {
      float4 qr[4], kr4[4];
#pragma unroll
      for (int a = 0; a < 4; ++a) qr[a] = *(float4*)&xb[swz4(4 * R + a, k4)];
#pragma unroll
      for (int b2 = 0; b2 < 4; ++b2)
        kr4[b2] = *(float4*)&kl[swz4(4 * Cc + b2, k4)];
#pragma unroll
      for (int a = 0; a < 4; ++a)
#pragma unroll
        for (int b2 = 0; b2 < 4; ++b2)
          acc[a][b2] += qr[a].x * kr4[b2].x + qr[a].y * kr4[b2].y +
                        qr[a].z * kr4[b2].z + qr[a].w * kr4[b2].w;
    }
    ushort* mbase = wMp + (size_t)cidx * C_ * C_;
#pragma unroll
    for (int a = 0; a < 4; ++a) {
      const int t = 4 * R + a;
      float tmp[4];
#pragma unroll
      for (int b2 = 0; b2 < 4; ++b2) {
        const int i = 4 * Cc + b2;
        tmp[b2] = (i <= t) ? acc[a][b2] * __expf(bG[t] - bG[i]) : 0.f;
      }
      uint2 ov; ov.x = pkbf(tmp[0], tmp[1]); ov.y = pkbf(tmp[2], tmp[3]);
      *(uint2*)&mbase[t * C_ + 4 * Cc] = ov;
    }
  }
  // ---- A (strictly lower), stored transposed
  if (Cc <= R) {
    float acc[4][4];
#pragma unroll
    for (int a = 0; a < 4; ++a)
#pragma unroll
      for (int b2 = 0; b2 < 4; ++b2) acc[a][b2] = 0.f;
    for (int k4 = 0; k4 < 64; ++k4) {
      float4 ar[4], br4[4];
#pragma unroll
      for (int a = 0; a < 4; ++a) ar[a] = *(float4*)&kl[swz4(4 * R + a, k4)];
#pragma unroll
      for (int b2 = 0; b2 < 4; ++b2)
        br4[b2] = *(float4*)&kl[swz4(4 * Cc + b2, k4)];
#pragma unroll
      for (int a = 0; a < 4; ++a)
#pragma unroll
        for (int b2 = 0; b2 < 4; ++b2)
          acc[a][b2] += ar[a].x * br4[b2].x + ar[a].y * br4[b2].y +
                        ar[a].z * br4[b2].z + ar[a].w * br4[b2].w;
    }
#pragma unroll
    for (int a = 0; a < 4; ++a) {
      const int t = 4 * R + a;
#pragma unroll
      for (int b2 = 0; b2 < 4; ++b2) {
        const int i = 4 * Cc + b2;
        AlT[i][t] = (i < t) ? bB[t] * __expf(bG[t] - bG[i]) * acc[a][b2] : 0.f;
      }
    }
  }
  __syncthreads();
#pragma unroll
  for (int rr = 0; rr < 16; ++rr) {
    const int row = rr * 4 + w;
    const float bbr = bB[row];
    const float sc = bbr * __expf(bG[row]);
    float4 kv = *(float4*)&kl[swz4(row, l)];
    kv.x *= sc; kv.y *= sc; kv.z *= sc; kv.w *= sc;
    *(float4*)&kl[swz4(row, l)] = kv;
    const size_t g0 = (srow0 + (size_t)row * H_) * DV_;
    float4 vv = *(const float4*)(v + g0 + 4 * l);
    vv.x *= bbr; vv.y *= bbr; vv.z *= bbr; vv.w *= bbr;
    *(float4*)&xb[swz4(row, l)] = vv;
  }
  __syncthreads();
  // ---- forward substitution (column tid on both RHS)
#pragma unroll
  for (int tb = 0; tb < 8; ++tb) {
    float xu[8], xw[8];
#pragma unroll
    for (int e = 0; e < 8; ++e) {
      xu[e] = xb[swzi(8 * tb + e, tid)];
      xw[e] = kl[swzi(8 * tb + e, tid)];
    }
    for (int i = 0; i < 8 * tb; ++i) {
      const float xui = xb[swzi(i, tid)];
      const float xwi = kl[swzi(i, tid)];
      float av[8];
      *(float4*)&av[0] = *(float4*)&AlT[i][8 * tb];
      *(float4*)&av[4] = *(float4*)&AlT[i][8 * tb + 4];
#pragma unroll
      for (int e = 0; e < 8; ++e) {
        xu[e] = fmaf(-av[e], xui, xu[e]);
        xw[e] = fmaf(-av[e], xwi, xw[e]);
      }
    }
#pragma unroll
    for (int e = 1; e < 8; ++e)
#pragma unroll
      for (int m = 0; m < 7; ++m)
        if (m < e) {
          const float am = AlT[8 * tb + m][8 * tb + e];
          xu[e] = fmaf(-am, xu[m], xu[e]);
          xw[e] = fmaf(-am, xw[m], xw[e]);
        }
#pragma unroll
    for (int e = 0; e < 8; ++e) {
      xb[swzi(8 * tb + e, tid)] = xu[e];
      kl[swzi(8 * tb + e, tid)] = xw[e];
    }
  }
  // ---- store W (bf16 row-major) and U (bf16 C/D-fragment packed pairs)
  {
    ushort* wb = wWp + (size_t)cidx * C_ * 256;
    for (int row = 0; row < C_; ++row)
      wb[row * 256 + tid] = (ushort)rnebf(kl[swzi(row, tid)]);
    const int cbw = tid >> 4, c16 = tid & 15;
#pragma unroll
    for (int mt = 0; mt < 4; ++mt) {
#pragma unroll
      for (int lgi = 0; lgi < 4; ++lgi) {
        const int r0 = 16 * mt + 4 * lgi;
        uint2 val;
        val.x = pkbf(xb[swzi(r0 + 0, tid)], xb[swzi(r0 + 1, tid)]);
        val.y = pkbf(xb[swzi(r0 + 2, tid)], xb[swzi(r0 + 3, tid)]);
        wUp[(((size_t)cidx * 16 + cbw) * 4 + mt) * 64 + (lgi << 4) + c16] = val;
      }
    }
  }
}

// ---------------------------------------------------------------------------
// Kernel 5 (sequential over chunks, MFMA): per (b,h, col-quarter) block,
// wave owns S[256 x 16] in fp32 accumulators. No LDS, no barriers.
// ---------------------------------------------------------------------------
__global__ __launch_bounds__(256) void gdn_seq_kernel(
    const ushort* __restrict__ wkT, const ushort* __restrict__ wQd,
    const ushort* __restrict__ wWp, const uint2* __restrict__ wUp,
    const float* __restrict__ Gc, uint2* __restrict__ wDP,
    float* __restrict__ o_raw) {
  const int bid = blockIdx.x;  // 48 = (bh, cb)
  const int bh = bid >> 2, cb = bid & 3;
  const int b = bh / H_, h = bh - b * H_;
  const int w = threadIdx.x >> 6, l = threadIdx.x & 63;
  const int lg = l >> 4, c16 = l & 15;
  const int cbw = cb * 4 + w;

  f32x4 S[16];
#pragma unroll
  for (int m2 = 0; m2 < 16; ++m2) S[m2] = (f32x4){0.f, 0.f, 0.f, 0.f};

  for (int nc = 0; nc < NC_; ++nc) {
    const int cidx = bh * NC_ + nc;
    const size_t t0 = (size_t)b * T_ + nc * C_;
    // pack S (state at chunk start) to bf16 C/D pairs
    uint2 P[16];
#pragma unroll
    for (int m2 = 0; m2 < 16; ++m2) {
      P[m2].x = pkbf(S[m2][0], S[m2][1]);
      P[m2].y = pkbf(S[m2][2], S[m2][3]);
    }
    f32x4 pA[4], oA[4];
#pragma unroll
    for (int mt = 0; mt < 4; ++mt) {
      pA[mt] = (f32x4){0.f, 0.f, 0.f, 0.f};
      oA[mt] = (f32x4){0.f, 0.f, 0.f, 0.f};
    }
    const ushort* Wb = wWp + (size_t)cidx * C_ * 256;
#pragma unroll
    for (int kt = 0; kt < 8; ++kt) {
      const short8 Bf = buildB(P[2 * kt], P[2 * kt + 1], lg, c16);
#pragma unroll
      for (int mt = 0; mt < 4; ++mt) {
        const uint4 aw =
            *(const uint4*)&Wb[(16 * mt + c16) * 256 + 32 * kt + 8 * lg];
        pA[mt] = __builtin_amdgcn_mfma_f32_16x16x32_bf16(u4_to_s8(aw), Bf,
                                                         pA[mt], 0, 0, 0);
      }
#pragma unroll
      for (int mt = 0; mt < 4; ++mt) {
        const uint4 aq = *(const uint4*)&wQd[((t0 + 16 * mt + c16) * H_ + h) *
                                                 (size_t)DK_ +
                                             32 * kt + 8 * lg];
        oA[mt] = __builtin_amdgcn_mfma_f32_16x16x32_bf16(u4_to_s8(aq), Bf,
                                                         oA[mt], 0, 0, 0);
      }
    }
    // delta = U - p (store bf16 pairs); o store (fp32 scatter)
    uint2 DP[4];
#pragma unroll
    for (int mt = 0; mt < 4; ++mt) {
      const size_t fidx = (((size_t)cidx * 16 + cbw) * 4 + mt) * 64 + l;
      const uint2 uu = wUp[fidx];
      const float d0 = bf2f(uu.x) - pA[mt][0];
      const float d1 = bf2f(uu.x >> 16) - pA[mt][1];
      const float d2 = bf2f(uu.y) - pA[mt][2];
      const float d3 = bf2f(uu.y >> 16) - pA[mt][3];
      DP[mt].x = pkbf(d0, d1);
      DP[mt].y = pkbf(d2, d3);
      wDP[fidx] = DP[mt];
#pragma unroll
      for (int r = 0; r < 4; ++r)
        o_raw[((t0 + 16 * mt + 4 * lg + r) * H_ + h) * (size_t)DV_ +
              cbw * 16 + c16] = oA[mt][r];
    }
    // S = lamC*S + Kd^T * delta
    const float lamC = __expf(Gc[cidx * C_ + C_ - 1]);
#pragma unroll
    for (int m2 = 0; m2 < 16; ++m2) {
      S[m2][0] *= lamC; S[m2][1] *= lamC; S[m2][2] *= lamC; S[m2][3] *= lamC;
    }
#pragma unroll
    for (int kt = 0; kt < 2; ++kt) {
      const short8 Bd = buildB(DP[2 * kt], DP[2 * kt + 1], lg, c16);
#pragma unroll
      for (int m2 = 0; m2 < 16; ++m2) {
        const uint4 ak =
            *(const uint4*)&wkT[((size_t)bh * 256 + 16 * m2 + c16) * T_ +
                                nc * C_ + 32 * kt + 8 * lg];
        S[m2] = __builtin_amdgcn_mfma_f32_16x16x32_bf16(u4_to_s8(ak), Bd,
                                                        S[m2], 0, 0, 0);
      }
    }
  }
}

// ---------------------------------------------------------------------------
// Kernel 6 (parallel, MFMA): o_raw += M * delta per (b,h,chunk)
// ---------------------------------------------------------------------------
__global__ __launch_bounds__(256) void gdn_oadd_kernel(
    const ushort* __restrict__ wMp, const uint2* __restrict__ wDP,
    float* __restrict__ o_raw) {
  const int bid = blockIdx.x;  // 384 = cidx
  const int bh = bid / NC_, nc = bid - bh * NC_;
  const int b = bh / H_, h = bh - b * H_;
  const int w = threadIdx.x >> 6, l = threadIdx.x & 63;
  const int lg = l >> 4, c16 = l & 15;
  const size_t t0 = (size_t)b * T_ + nc * C_;
  const ushort* Mb = wMp + (size_t)bid * C_ * C_;

  uint2 DPl[4][4];
#pragma unroll
  for (int nt = 0; nt < 4; ++nt)
#pragma unroll
    for (int mt = 0; mt < 4; ++mt)
      DPl[nt][mt] =
          wDP[(((size_t)bid * 16 + 4 * w + nt) * 4 + mt) * 64 + l];

  f32x4 acc[4][4];
#pragma unroll
  for (int mt = 0; mt < 4; ++mt)
#pragma unroll
    for (int nt = 0; nt < 4; ++nt)
#pragma unroll
      for (int r = 0; r < 4; ++r)
        acc[mt][nt][r] = o_raw[((t0 + 16 * mt + 4 * lg + r) * H_ + h) *
                                   (size_t)DV_ +
                               (4 * w + nt) * 16 + c16];

#pragma unroll
  for (int nt = 0; nt < 4; ++nt)
#pragma unroll
    for (int kt = 0; kt < 2; ++kt) {
      const short8 Bf = buildB(DPl[nt][2 * kt], DPl[nt][2 * kt + 1], lg, c16);
#pragma unroll
      for (int mt = 0; mt < 4; ++mt) {
        const uint4 am =
            *(const uint4*)&Mb[(16 * mt + c16) * C_ + 32 * kt + 8 * lg];
        acc[mt][nt] = __builtin_amdgcn_mfma_f32_16x16x32_bf16(
            u4_to_s8(am), Bf, acc[mt][nt], 0, 0, 0);
      }
    }

#pragma unroll
  for (int mt = 0; mt < 4; ++mt)
#pragma unroll
    for (int nt = 0; nt < 4; ++nt)
#pragma unroll
      for (int r = 0; r < 4; ++r)
        o_raw[((t0 + 16 * mt + 4 * lg + r) * H_ + h) * (size_t)DV_ +
              (4 * w + nt) * 16 + c16] = acc[mt][nt][r];
}

// ---------------------------------------------------------------------------
// Kernel 7: RMSNorm * norm_w * swish(gate), per-head GroupLinear (unchanged)
// ---------------------------------------------------------------------------
__global__ __launch_bounds__(256) void gdn_out_kernel(
    const float* __restrict__ o_raw, const float* __restrict__ sgate,
    const float* __restrict__ norm_w, const float* __restrict__ o_w,
    float* __restrict__ out) {
  const int tile = blockIdx.x;
  const int h = blockIdx.y;
  const int tid = threadIdx.x;
  const int lane = tid & 63;
  const int wid = tid >> 6;

  __shared__ float on[16][DV_];
  __shared__ float red[16][4];
  __shared__ float rms_s[16];
  __shared__ float sgs_s[16];

  float x[16];
#pragma unroll
  for (int tt = 0; tt < 16; ++tt) {
    x[tt] = o_raw[((size_t)(tile * 16 + tt) * H_ + h) * DV_ + tid];
  }

#pragma unroll
  for (int tt = 0; tt < 16; ++tt) {
    float ssv = x[tt] * x[tt];
    ssv += __shfl_xor(ssv, 1);
    ssv += __shfl_xor(ssv, 2);
    ssv += __shfl_xor(ssv, 4);
    ssv += __shfl_xor(ssv, 8);
    ssv += __shfl_xor(ssv, 16);
    ssv += __shfl_xor(ssv, 32);
    if (lane == 0) red[tt][wid] = ssv;
  }
  __syncthreads();
  if (tid < 16) {
    const float ms =
        (red[tid][0] + red[tid][1] + red[tid][2] + red[tid][3]) * (1.f / DV_);
    rms_s[tid] = rsqrtf(ms + 1e-5f);
    sgs_s[tid] = sgate[(size_t)(tile * 16 + tid) * H_ + h];
  }
  __syncthreads();

  const float nw = norm_w[tid];
#pragma unroll
  for (int tt = 0; tt < 16; ++tt) {
    on[tt][tid] = x[tt] * rms_s[tt] * nw * sgs_s[tt];
  }
  __syncthreads();

  float acc[16];
#pragma unroll
  for (int tt = 0; tt < 16; ++tt) acc[tt] = 0.f;

  const float* wp = o_w + (size_t)h * DV_ * DK_ + tid;
  for (int v4 = 0; v4 < DV_ / 4; ++v4) {
    const float w0 = wp[(4 * v4 + 0) * DK_];
    const float w1 = wp[(4 * v4 + 1) * DK_];
    const float w2 = wp[(4 * v4 + 2) * DK_];
    const float w3 = wp[(4 * v4 + 3) * DK_];
#pragma unroll
    for (int tt = 0; tt < 16; ++tt) {
      const float4 ov = *(const float4*)&on[tt][4 * v4];
      acc[tt] = fmaf(ov.x, w0,
                fmaf(ov.y, w1, fmaf(ov.z, w2, fmaf(ov.w, w3, acc[tt]))));
    }
  }

#pragma unroll
  for (int tt = 0; tt < 16; ++tt) {
    out[((size_t)(tile * 16 + tt) * H_ + h) * DK_ + tid] = acc[tt];
  }
}

// ---------------------------------------------------------------------------
extern "C" void kernel_launch(void* const* d_in, const int* in_sizes, int n_in,
                              void* d_out, int out_size, void* d_ws,
                              size_t ws_size, hipStream_t stream) {
  const float* hab = (const float*)d_in[0];
  const float* hg = (const float*)d_in[1];
  const float* q = (const float*)d_in[2];
  const float* k = (const float*)d_in[3];
  const float* v = (const float*)d_in[4];
  const float* b_w = (const float*)d_in[5];
  const float* a_w = (const float*)d_in[6];
  const float* A_log = (const float*)d_in[7];
  const float* dt_bias = (const float*)d_in[8];
  const float* g_w = (const float*)d_in[9];
  const float* norm_w = (const float*)d_in[10];
  const float* o_w = (const float*)d_in[11];
  float* out = (float*)d_out;

  float* ws = (float*)d_ws;
  const size_t NBT = (size_t)B_ * T_ * H_;  // 24576
  float* w_beta = ws;
  float* w_g = ws + NBT;
  float* w_sg = ws + 2 * NBT;
  float* w_sq = ws + 3 * NBT;
  float* w_sk = ws + 4 * NBT;
  float* w_G = ws + 5 * NBT;
  float* w_sqe = ws + 6 * NBT;
  ushort* w_Qd = (ushort*)(ws + 7 * NBT);            // 12,582,912 u16
  ushort* w_kT = w_Qd + (size_t)12582912;            // 6,291,456 u16
  ushort* w_W = w_kT + (size_t)6291456;              // 6,291,456 u16
  ushort* w_M = w_W + (size_t)6291456;               // 1,572,864 u16
  uint2* w_U = (uint2*)(w_M + (size_t)1572864);      // 1,572,864 uint2
  uint2* w_DP = w_U + (size_t)1572864;               // 1,572,864 uint2
  float* w_o = (float*)(w_DP + (size_t)1572864);     // 12,582,912 f32

  hipLaunchKernelGGL(gdn_proj_kernel, dim3(B_ * T_), dim3(256), 0, stream,
                     hab, hg, b_w, a_w, g_w, A_log, dt_bias, w_beta, w_g, w_sg);
  hipLaunchKernelGGL(gdn_norm_kernel, dim3(B_ * T_ * H_ / 4), dim3(256), 0,
                     stream, q, k, w_sq, w_sk);
  hipLaunchKernelGGL(gdn_cum_kernel, dim3(B_ * H_), dim3(256), 0, stream,
                     w_g, w_sq, w_G, w_sqe);
  hipLaunchKernelGGL(gdn_qscale_kernel,
                     dim3((B_ * T_ * H_ * DK_) / (8 * 256)), dim3(256), 0,
                     stream, q, w_sqe, w_Qd);
  hipLaunchKernelGGL(gdn_ktrans_kernel, dim3(B_ * H_ * NC_), dim3(256), 0,
                     stream, k, w_sk, w_G, w_kT);
  hipLaunchKernelGGL(gdn_prep_kernel, dim3(B_ * H_ * NC_), dim3(256), 0,
                     stream, q, k, v, w_beta, w_sq, w_sk, w_G, w_U, w_W, w_M);
  hipLaunchKernelGGL(gdn_seq_kernel, dim3(B_ * H_ * 4), dim3(256), 0, stream,
                     w_kT, w_Qd, w_W, w_U, w_G, w_DP, w_o);
  hipLaunchKernelGGL(gdn_oadd_kernel, dim3(B_ * H_ * NC_), dim3(256), 0,
                     stream, w_M, w_DP, w_o);
  hipLaunchKernelGGL(gdn_out_kernel, dim3(B_ * T_ / 16, H_), dim3(256), 0,
                     stream, w_o, w_sg, norm_w, o_w, out);
}

// Round 4
// 437.010 us; speedup vs baseline: 5.5709x; 2.0000x over previous
//
#include <hip/hip_runtime.h>
#include <hip/hip_bf16.h>
#include <math.h>

#define B_ 2
#define T_ 2048
#define H_ 6
#define DK_ 256
#define DV_ 256
#define HID_ 2048
#define C_ 64
#define NC_ 32

typedef __attribute__((ext_vector_type(8))) short short8;
typedef __attribute__((ext_vector_type(4))) float f32x4;

__device__ __forceinline__ unsigned rnebf(float f) {
  unsigned u = __float_as_uint(f);
  return (u + 0x7fffu + ((u >> 16) & 1u)) >> 16;
}
__device__ __forceinline__ unsigned pkbf(float lo, float hi) {
  return rnebf(lo) | (rnebf(hi) << 16);
}
__device__ __forceinline__ float bf2f(unsigned u16v) {
  return __uint_as_float((u16v & 0xffffu) << 16);
}
__device__ __forceinline__ short8 u4_to_s8(uint4 u) {
  union { uint4 u; short8 s; } c; c.u = u; return c.s;
}

// async global->LDS 16B per lane; LDS dest wave-uniform base + lane*16
__device__ __forceinline__ void gload_lds16(const void* g, void* l) {
  __builtin_amdgcn_global_load_lds(
      (const __attribute__((address_space(1))) unsigned int*)g,
      (__attribute__((address_space(3))) unsigned int*)l, 16, 0, 0);
}

// Build MFMA B-fragment (16x16x32 bf16) for k-tile from two C/D-layout packed
// mtiles Pe (even, rows 32kt..32kt+15) and Po (odd, rows +16..+31).
__device__ __forceinline__ short8 buildB(uint2 Pe, uint2 Po, int lg, int c16) {
  const int src0 = ((2 * (lg & 1)) << 4) | c16;
  const int src1 = src0 + 16;
  int e0 = __shfl((int)Pe.x, src0), o0 = __shfl((int)Po.x, src0);
  int e1 = __shfl((int)Pe.y, src0), o1 = __shfl((int)Po.y, src0);
  int e2 = __shfl((int)Pe.x, src1), o2 = __shfl((int)Po.x, src1);
  int e3 = __shfl((int)Pe.y, src1), o3 = __shfl((int)Po.y, src1);
  const bool lo2 = (lg < 2);
  union { int i[4]; short8 s; } u;
  u.i[0] = lo2 ? e0 : o0;
  u.i[1] = lo2 ? e1 : o1;
  u.i[2] = lo2 ? e2 : o2;
  u.i[3] = lo2 ? e3 : o3;
  return u.s;
}

// ---------------------------------------------------------------------------
// Kernel 1: fused projections (unchanged)
// ---------------------------------------------------------------------------
__global__ __launch_bounds__(256) void gdn_proj_kernel(
    const float* __restrict__ hab, const float* __restrict__ hg,
    const float* __restrict__ b_w, const float* __restrict__ a_w,
    const float* __restrict__ g_w, const float* __restrict__ A_log,
    const float* __restrict__ dt_bias,
    float* __restrict__ beta_o, float* __restrict__ g_o,
    float* __restrict__ sgate_o) {
  const int bt = blockIdx.x;
  const int tid = threadIdx.x;
  const int lane = tid & 63;
  const int wid = tid >> 6;

  const float* h1 = hab + (size_t)bt * HID_ + tid * 8;
  const float* h2 = hg + (size_t)bt * HID_ + tid * 8;
  const float4 xa = *(const float4*)(h1);
  const float4 xb = *(const float4*)(h1 + 4);
  const float4 ya = *(const float4*)(h2);
  const float4 yb = *(const float4*)(h2 + 4);

  float part[18];
#pragma unroll
  for (int n = 0; n < 6; ++n) {
    const float* wp = b_w + n * HID_ + tid * 8;
    const float4 w0 = *(const float4*)(wp);
    const float4 w1 = *(const float4*)(wp + 4);
    part[n] = xa.x * w0.x + xa.y * w0.y + xa.z * w0.z + xa.w * w0.w +
              xb.x * w1.x + xb.y * w1.y + xb.z * w1.z + xb.w * w1.w;
  }
#pragma unroll
  for (int n = 0; n < 6; ++n) {
    const float* wp = a_w + n * HID_ + tid * 8;
    const float4 w0 = *(const float4*)(wp);
    const float4 w1 = *(const float4*)(wp + 4);
    part[6 + n] = xa.x * w0.x + xa.y * w0.y + xa.z * w0.z + xa.w * w0.w +
                  xb.x * w1.x + xb.y * w1.y + xb.z * w1.z + xb.w * w1.w;
  }
#pragma unroll
  for (int n = 0; n < 6; ++n) {
    const float* wp = g_w + n * HID_ + tid * 8;
    const float4 w0 = *(const float4*)(wp);
    const float4 w1 = *(const float4*)(wp + 4);
    part[12 + n] = ya.x * w0.x + ya.y * w0.y + ya.z * w0.z + ya.w * w0.w +
                   yb.x * w1.x + yb.y * w1.y + yb.z * w1.z + yb.w * w1.w;
  }

  __shared__ float red[18][4];
#pragma unroll
  for (int i = 0; i < 18; ++i) {
    float x = part[i];
    x += __shfl_xor(x, 1);
    x += __shfl_xor(x, 2);
    x += __shfl_xor(x, 4);
    x += __shfl_xor(x, 8);
    x += __shfl_xor(x, 16);
    x += __shfl_xor(x, 32);
    if (lane == 0) red[i][wid] = x;
  }
  __syncthreads();

  if (tid < 18) {
    const float s = red[tid][0] + red[tid][1] + red[tid][2] + red[tid][3];
    if (tid < 6) {
      beta_o[(size_t)bt * H_ + tid] = 1.f / (1.f + __expf(-s));
    } else if (tid < 12) {
      const int n = tid - 6;
      const float x = s + dt_bias[n];
      const float sp = (x > 20.f) ? x : log1pf(__expf(x));
      g_o[(size_t)bt * H_ + n] = -__expf(A_log[n]) * sp;
    } else {
      const int n = tid - 12;
      sgate_o[(size_t)bt * H_ + n] = s / (1.f + __expf(-s));
    }
  }
}

// ---------------------------------------------------------------------------
// Kernel 2: q/k inverse L2 norms (unchanged)
// ---------------------------------------------------------------------------
__global__ __launch_bounds__(256) void gdn_norm_kernel(
    const float* __restrict__ q, const float* __restrict__ k,
    float* __restrict__ sq, float* __restrict__ sk) {
  const int gw = blockIdx.x * 4 + (threadIdx.x >> 6);
  const int lane = threadIdx.x & 63;

  const float4 qv = *(const float4*)(q + (size_t)gw * DK_ + lane * 4);
  const float4 kv = *(const float4*)(k + (size_t)gw * DK_ + lane * 4);
  float sums_q = qv.x * qv.x + qv.y * qv.y + qv.z * qv.z + qv.w * qv.w;
  float sums_k = kv.x * kv.x + kv.y * kv.y + kv.z * kv.z + kv.w * kv.w;
#pragma unroll
  for (int m = 1; m < 64; m <<= 1) {
    sums_q += __shfl_xor(sums_q, m);
    sums_k += __shfl_xor(sums_k, m);
  }
  if (lane == 0) {
    sq[gw] = rsqrtf(sums_q + 1e-6f) * 0.0625f;
    sk[gw] = rsqrtf(sums_k + 1e-6f);
  }
}

// ---------------------------------------------------------------------------
// Kernel 3: per-chunk inclusive cumsum of g; also sqe = sq*exp(G)
// ---------------------------------------------------------------------------
__global__ __launch_bounds__(256) void gdn_cum_kernel(
    const float* __restrict__ g, const float* __restrict__ sq,
    float* __restrict__ Gc, float* __restrict__ sqe) {
  const int bh = blockIdx.x;
  const int b = bh / H_, h = bh - b * H_;
  const int w = threadIdx.x >> 6, l = threadIdx.x & 63;
  for (int it = 0; it < 8; ++it) {
    const int nc = it * 4 + w;
    const int tg = nc * C_ + l;
    const size_t srow = ((size_t)b * T_ + tg) * H_ + h;
    float val = g[srow];
#pragma unroll
    for (int ofs = 1; ofs < 64; ofs <<= 1) {
      const float o = __shfl_up(val, ofs);
      if (l >= ofs) val += o;
    }
    Gc[(bh * NC_ + nc) * C_ + l] = val;
    sqe[srow] = sq[srow] * __expf(val);
  }
}

// ---------------------------------------------------------------------------
// Kernel 3b: Qd = q * sqe  (bf16, row-major [B,T,H,DK])
// ---------------------------------------------------------------------------
__global__ __launch_bounds__(256) void gdn_qscale_kernel(
    const float* __restrict__ q, const float* __restrict__ sqe,
    ushort* __restrict__ wQd) {
  const size_t i8 = (size_t)blockIdx.x * 256 + threadIdx.x;
  const size_t i0 = i8 * 8;
  const float s = sqe[i8 >> 5];
  const float4 a = *(const float4*)(q + i0);
  const float4 b = *(const float4*)(q + i0 + 4);
  uint4 o;
  o.x = pkbf(a.x * s, a.y * s);
  o.y = pkbf(a.z * s, a.w * s);
  o.z = pkbf(b.x * s, b.y * s);
  o.w = pkbf(b.z * s, b.w * s);
  *(uint4*)&wQd[i0] = o;
}

// ---------------------------------------------------------------------------
// Kernel 3c: kT tiles: [cidx][d(256)][t(64)] bf16, scale exp(gend-G)*sk folded
// ---------------------------------------------------------------------------
__global__ __launch_bounds__(256) void gdn_ktrans_kernel(
    const float* __restrict__ k, const float* __restrict__ sk,
    const float* __restrict__ Gc, ushort* __restrict__ wkT) {
  const int bid = blockIdx.x;
  const int bh = bid / NC_, nc = bid - bh * NC_;
  const int b = bh / H_, h = bh - b * H_;
  const int tid = threadIdx.x;
  const int cidx = bh * NC_ + nc;
  const size_t srow0 = ((size_t)b * T_ + nc * C_) * H_ + h;

  __shared__ ushort ldsT[256 * 68];
  const float gend = Gc[cidx * C_ + C_ - 1];

#pragma unroll
  for (int p = 0; p < 4; ++p) {
    const int t = p * 16 + (tid >> 4);
    const float scale =
        __expf(gend - Gc[cidx * C_ + t]) * sk[srow0 + (size_t)t * H_];
#pragma unroll
    for (int s = 0; s < 4; ++s) {
      const int col = 64 * s + 4 * (tid & 15);
      const float4 kv = *(const float4*)(k + (srow0 + (size_t)t * H_) * DK_ + col);
      ldsT[(col + 0) * 68 + t] = (ushort)rnebf(kv.x * scale);
      ldsT[(col + 1) * 68 + t] = (ushort)rnebf(kv.y * scale);
      ldsT[(col + 2) * 68 + t] = (ushort)rnebf(kv.z * scale);
      ldsT[(col + 3) * 68 + t] = (ushort)rnebf(kv.w * scale);
    }
  }
  __syncthreads();

  const int e = tid & 7;
#pragma unroll
  for (int p = 0; p < 8; ++p) {
    const int d = p * 32 + (tid >> 3);
    uint2 lo = *(uint2*)&ldsT[d * 68 + 8 * e];
    uint2 hi = *(uint2*)&ldsT[d * 68 + 8 * e + 4];
    uint4 o; o.x = lo.x; o.y = lo.y; o.z = hi.x; o.w = hi.y;
    *(uint4*)&wkT[((size_t)cidx * 256 + d) * C_ + 8 * e] = o;
  }
}

// LDS XOR swizzle for prep tiles
__device__ __forceinline__ int swz4(int row, int c4) {
  return row * 256 + (((c4) ^ ((row >> 2) & 7)) << 2);
}
__device__ __forceinline__ int swzi(int row, int c) {
  return row * 256 + ((((c) >> 2) ^ ((row >> 2) & 7)) << 2) + ((c) & 3);
}

// ---------------------------------------------------------------------------
// Kernel 4 (parallel, per (b,h,chunk)): A, M, forward-substitution -> U, W.
// (unchanged from R3)
// ---------------------------------------------------------------------------
__global__ __launch_bounds__(256) void gdn_prep_kernel(
    const float* __restrict__ q, const float* __restrict__ k,
    const float* __restrict__ v, const float* __restrict__ beta,
    const float* __restrict__ sq, const float* __restrict__ sk,
    const float* __restrict__ Gc, uint2* __restrict__ wUp,
    ushort* __restrict__ wWp, ushort* __restrict__ wMp) {
  const int bid = blockIdx.x;
  const int bh = bid / NC_;
  const int nc = bid - bh * NC_;
  const int b = bh / H_, h = bh - b * H_;
  const int tid = threadIdx.x;
  const int w = tid >> 6, l = tid & 63;
  const int cidx = bh * NC_ + nc;

  __shared__ float kl[C_ * 256];
  __shared__ float xb[C_ * 256];
  __shared__ float AlT[C_][68];
  __shared__ float bG[C_], bB[C_];

  const size_t srow0 = ((size_t)b * T_ + nc * C_) * H_ + h;
  if (tid < C_) {
    bG[tid] = Gc[cidx * C_ + tid];
    bB[tid] = beta[srow0 + (size_t)tid * H_];
  }
#pragma unroll
  for (int rr = 0; rr < 16; ++rr) {
    const int row = rr * 4 + w;
    const size_t g0 = (srow0 + (size_t)row * H_) * DK_;
    const float skr = sk[srow0 + (size_t)row * H_];
    const float sqr = sq[srow0 + (size_t)row * H_];
    float4 kv = *(const float4*)(k + g0 + 4 * l);
    float4 qv = *(const float4*)(q + g0 + 4 * l);
    kv.x *= skr; kv.y *= skr; kv.z *= skr; kv.w *= skr;
    qv.x *= sqr; qv.y *= sqr; qv.z *= sqr; qv.w *= sqr;
    *(float4*)&kl[swz4(row, l)] = kv;
    *(float4*)&xb[swz4(row, l)] = qv;
  }
  __syncthreads();

  const int R = tid >> 4, Cc = tid & 15;
  // ---- M = masked(exp(Gt-Gi) * qn kn^T), i <= t  (bf16 row-major)
  {
    float acc[4][4];
#pragma unroll
    for (int a = 0; a < 4; ++a)
#pragma unroll
      for (int b2 = 0; b2 < 4; ++b2) acc[a][b2] = 0.f;
    for (int k4 = 0; k4 < 64; ++k4) {
      float4 qr[4], kr4[4];
#pragma unroll
      for (int a = 0; a < 4; ++a) qr[a] = *(float4*)&xb[swz4(4 * R + a, k4)];
#pragma unroll
      for (int b2 = 0; b2 < 4; ++b2)
        kr4[b2] = *(float4*)&kl[swz4(4 * Cc + b2, k4)];
#pragma unroll
      for (int a = 0; a < 4; ++a)
#pragma unroll
        for (int b2 = 0; b2 < 4; ++b2)
          acc[a][b2] += qr[a].x * kr4[b2].x + qr[a].y * kr4[b2].y +
                        qr[a].z * kr4[b2].z + qr[a].w * kr4[b2].w;
    }
    ushort* mbase = wMp + (size_t)cidx * C_ * C_;
#pragma unroll
    for (int a = 0; a < 4; ++a) {
      const int t = 4 * R + a;
      float tmp[4];
#pragma unroll
      for (int b2 = 0; b2 < 4; ++b2) {
        const int i = 4 * Cc + b2;
        tmp[b2] = (i <= t) ? acc[a][b2] * __expf(bG[t] - bG[i]) : 0.f;
      }
      uint2 ov; ov.x = pkbf(tmp[0], tmp[1]); ov.y = pkbf(tmp[2], tmp[3]);
      *(uint2*)&mbase[t * C_ + 4 * Cc] = ov;
    }
  }
  // ---- A (strictly lower), stored transposed
  if (Cc <= R) {
    float acc[4][4];
#pragma unroll
    for (int a = 0; a < 4; ++a)
#pragma unroll
      for (int b2 = 0; b2 < 4; ++b2) acc[a][b2] = 0.f;
    for (int k4 = 0; k4 < 64; ++k4) {
      float4 ar[4], br4[4];
#pragma unroll
      for (int a = 0; a < 4; ++a) ar[a] = *(float4*)&kl[swz4(4 * R + a, k4)];
#pragma unroll
      for (int b2 = 0; b2 < 4; ++b2)
        br4[b2] = *(float4*)&kl[swz4(4 * Cc + b2, k4)];
#pragma unroll
      for (int a = 0; a < 4; ++a)
#pragma unroll
        for (int b2 = 0; b2 < 4; ++b2)
          acc[a][b2] += ar[a].x * br4[b2].x + ar[a].y * br4[b2].y +
                        ar[a].z * br4[b2].z + ar[a].w * br4[b2].w;
    }
#pragma unroll
    for (int a = 0; a < 4; ++a) {
      const int t = 4 * R + a;
#pragma unroll
      for (int b2 = 0; b2 < 4; ++b2) {
        const int i = 4 * Cc + b2;
        AlT[i][t] = (i < t) ? bB[t] * __expf(bG[t] - bG[i]) * acc[a][b2] : 0.f;
      }
    }
  }
  __syncthreads();
#pragma unroll
  for (int rr = 0; rr < 16; ++rr) {
    const int row = rr * 4 + w;
    const float bbr = bB[row];
    const float sc = bbr * __expf(bG[row]);
    float4 kv = *(float4*)&kl[swz4(row, l)];
    kv.x *= sc; kv.y *= sc; kv.z *= sc; kv.w *= sc;
    *(float4*)&kl[swz4(row, l)] = kv;
    const size_t g0 = (srow0 + (size_t)row * H_) * DV_;
    float4 vv = *(const float4*)(v + g0 + 4 * l);
    vv.x *= bbr; vv.y *= bbr; vv.z *= bbr; vv.w *= bbr;
    *(float4*)&xb[swz4(row, l)] = vv;
  }
  __syncthreads();
  // ---- forward substitution (column tid on both RHS)
#pragma unroll
  for (int tb = 0; tb < 8; ++tb) {
    float xu[8], xw[8];
#pragma unroll
    for (int e = 0; e < 8; ++e) {
      xu[e] = xb[swzi(8 * tb + e, tid)];
      xw[e] = kl[swzi(8 * tb + e, tid)];
    }
    for (int i = 0; i < 8 * tb; ++i) {
      const float xui = xb[swzi(i, tid)];
      const float xwi = kl[swzi(i, tid)];
      float av[8];
      *(float4*)&av[0] = *(float4*)&AlT[i][8 * tb];
      *(float4*)&av[4] = *(float4*)&AlT[i][8 * tb + 4];
#pragma unroll
      for (int e = 0; e < 8; ++e) {
        xu[e] = fmaf(-av[e], xui, xu[e]);
        xw[e] = fmaf(-av[e], xwi, xw[e]);
      }
    }
#pragma unroll
    for (int e = 1; e < 8; ++e)
#pragma unroll
      for (int m = 0; m < 7; ++m)
        if (m < e) {
          const float am = AlT[8 * tb + m][8 * tb + e];
          xu[e] = fmaf(-am, xu[m], xu[e]);
          xw[e] = fmaf(-am, xw[m], xw[e]);
        }
#pragma unroll
    for (int e = 0; e < 8; ++e) {
      xb[swzi(8 * tb + e, tid)] = xu[e];
      kl[swzi(8 * tb + e, tid)] = xw[e];
    }
  }
  // ---- store W (bf16 row-major) and U (bf16 C/D-fragment packed pairs)
  {
    ushort* wb = wWp + (size_t)cidx * C_ * 256;
    for (int row = 0; row < C_; ++row)
      wb[row * 256 + tid] = (ushort)rnebf(kl[swzi(row, tid)]);
    const int cbw = tid >> 4, c16 = tid & 15;
#pragma unroll
    for (int mt = 0; mt < 4; ++mt) {
#pragma unroll
      for (int lgi = 0; lgi < 4; ++lgi) {
        const int r0 = 16 * mt + 4 * lgi;
        uint2 val;
        val.x = pkbf(xb[swzi(r0 + 0, tid)], xb[swzi(r0 + 1, tid)]);
        val.y = pkbf(xb[swzi(r0 + 2, tid)], xb[swzi(r0 + 3, tid)]);
        wUp[(((size_t)cidx * 16 + cbw) * 4 + mt) * 64 + (lgi << 4) + c16] = val;
      }
    }
  }
}

// ---------------------------------------------------------------------------
// Kernel 5 (sequential over chunks, MFMA + LDS pipeline):
// 24 blocks = (bh, half); 8 waves; wave owns S[256 x 16] (cbw = half*8+w).
// Operands W/kT/U prefetched 2 chunks ahead via global_load_lds, counted vmcnt.
// ---------------------------------------------------------------------------
__global__ __launch_bounds__(512) void gdn_seq_kernel(
    const ushort* __restrict__ wkT, const ushort* __restrict__ wWp,
    const uint2* __restrict__ wUp, const float* __restrict__ Gc,
    uint2* __restrict__ wDP, uint2* __restrict__ wSP) {
  const int bid = blockIdx.x;
  const int bh = bid >> 1, half = bid & 1;
  const int tid = threadIdx.x;
  const int w = tid >> 6, l = tid & 63;
  const int lg = l >> 4, c16 = l & 15;
  const int cbw = half * 8 + w;
  const int xorv = (c16 & 7) << 4;

  __shared__ ushort sW[2][16384];  // 2 x 32 KB  (rows 512 B, XOR-swizzled)
  __shared__ ushort sK[2][16384];  // 2 x 32 KB  (rows 128 B, XOR-swizzled)
  __shared__ uint2 sU[2][2048];    // 2 x 16 KB  (linear)

  // ---- staging (each wave issues exactly 10 global_load_lds per chunk)
  auto stage = [&](int pp, int cidx2) {
    const char* gw_ = (const char*)(wWp + (size_t)cidx2 * 16384);
#pragma unroll
    for (int j = 0; j < 4; ++j) {
      const int i = w * 4 + j;
      const int row = 2 * i + (l >> 5);
      const int colb = ((l & 31) * 16) ^ ((row & 7) << 4);
      gload_lds16(gw_ + row * 512 + colb, (char*)&sW[pp][0] + i * 1024);
    }
    const char* gk_ = (const char*)(wkT + (size_t)cidx2 * 16384);
#pragma unroll
    for (int j = 0; j < 4; ++j) {
      const int i = w * 4 + j;
      const int row = 8 * i + (l >> 3);
      const int colb = ((l & 7) * 16) ^ ((row & 7) << 4);
      gload_lds16(gk_ + row * 128 + colb, (char*)&sK[pp][0] + i * 1024);
    }
    const char* gu_ = (const char*)wUp + (size_t)cidx2 * 32768 + half * 16384;
#pragma unroll
    for (int j = 0; j < 2; ++j) {
      const int i = w * 2 + j;
      gload_lds16(gu_ + i * 1024 + l * 16, (char*)&sU[pp][0] + i * 1024);
    }
  };

  f32x4 S[16];
#pragma unroll
  for (int m2 = 0; m2 < 16; ++m2) S[m2] = (f32x4){0.f, 0.f, 0.f, 0.f};

  stage(0, bh * NC_ + 0);
  stage(1, bh * NC_ + 1);
  float gcur = Gc[(bh * NC_) * C_ + C_ - 1];
  __builtin_amdgcn_sched_barrier(0);

  for (int nc = 0; nc < NC_; ++nc) {
    const int pp = nc & 1;
    const int cidx = bh * NC_ + nc;
    // buf[pp] ready: 10 newest outstanding vmem = next chunk's batch
    asm volatile("s_waitcnt vmcnt(10)" ::: "memory");
    __builtin_amdgcn_sched_barrier(0);
    __builtin_amdgcn_s_barrier();
    __builtin_amdgcn_sched_barrier(0);

    // pack S (chunk-start state) -> P; store checkpoint
    uint2 P[16];
#pragma unroll
    for (int m2 = 0; m2 < 16; ++m2) {
      P[m2].x = pkbf(S[m2][0], S[m2][1]);
      P[m2].y = pkbf(S[m2][2], S[m2][3]);
      wSP[(((size_t)cidx * 16 + cbw) * 16 + m2) * 64 + l] = P[m2];
    }
    float gnext = 0.f;
    if (nc + 1 < NC_) gnext = Gc[(cidx + 1) * C_ + C_ - 1];

    // GEMM1: p = W * S  (even/odd split accumulators -> 4-deep chain)
    f32x4 pe[4], po[4];
#pragma unroll
    for (int mt = 0; mt < 4; ++mt) {
      pe[mt] = (f32x4){0.f, 0.f, 0.f, 0.f};
      po[mt] = (f32x4){0.f, 0.f, 0.f, 0.f};
    }
    const char* sWb = (const char*)&sW[pp][0];
#pragma unroll
    for (int kt = 0; kt < 8; ++kt) {
      const short8 Bf = buildB(P[2 * kt], P[2 * kt + 1], lg, c16);
      const int colb = (64 * kt + 16 * lg) ^ xorv;
#pragma unroll
      for (int mt = 0; mt < 4; ++mt) {
        const uint4 aw = *(const uint4*)(sWb + (16 * mt + c16) * 512 + colb);
        if (kt & 1)
          po[mt] = __builtin_amdgcn_mfma_f32_16x16x32_bf16(u4_to_s8(aw), Bf,
                                                           po[mt], 0, 0, 0);
        else
          pe[mt] = __builtin_amdgcn_mfma_f32_16x16x32_bf16(u4_to_s8(aw), Bf,
                                                           pe[mt], 0, 0, 0);
      }
    }
    // delta = U - p
    uint2 DP[4];
#pragma unroll
    for (int mt = 0; mt < 4; ++mt) {
      const uint2 uu = sU[pp][(w * 4 + mt) * 64 + l];
      const float d0 = bf2f(uu.x) - (pe[mt][0] + po[mt][0]);
      const float d1 = bf2f(uu.x >> 16) - (pe[mt][1] + po[mt][1]);
      const float d2 = bf2f(uu.y) - (pe[mt][2] + po[mt][2]);
      const float d3 = bf2f(uu.y >> 16) - (pe[mt][3] + po[mt][3]);
      DP[mt].x = pkbf(d0, d1);
      DP[mt].y = pkbf(d2, d3);
      wDP[(((size_t)cidx * 16 + cbw) * 4 + mt) * 64 + l] = DP[mt];
    }
    // S = lamC*S + Kd^T * delta
    const float lamC = __expf(gcur);
#pragma unroll
    for (int m2 = 0; m2 < 16; ++m2) {
      S[m2][0] *= lamC; S[m2][1] *= lamC; S[m2][2] *= lamC; S[m2][3] *= lamC;
    }
    const char* sKb = (const char*)&sK[pp][0];
#pragma unroll
    for (int kt = 0; kt < 2; ++kt) {
      const short8 Bd = buildB(DP[2 * kt], DP[2 * kt + 1], lg, c16);
      const int colb = (64 * kt + 16 * lg) ^ xorv;
#pragma unroll
      for (int m2 = 0; m2 < 16; ++m2) {
        const uint4 ak = *(const uint4*)(sKb + (16 * m2 + c16) * 128 + colb);
        S[m2] = __builtin_amdgcn_mfma_f32_16x16x32_bf16(u4_to_s8(ak), Bd,
                                                        S[m2], 0, 0, 0);
      }
    }
    gcur = gnext;
    // all waves done reading buf[pp]
    __builtin_amdgcn_sched_barrier(0);
    __builtin_amdgcn_s_barrier();
    __builtin_amdgcn_sched_barrier(0);
    if (nc + 2 < NC_) stage(pp, cidx + 2);
    __builtin_amdgcn_sched_barrier(0);
  }
}

// ---------------------------------------------------------------------------
// Kernel 6 (parallel, MFMA): o = Qd * S_chk + M * delta, per (b,h,chunk).
// S_chk staged to LDS first; o written over the same ws slot (tiled layout).
// ---------------------------------------------------------------------------
__global__ __launch_bounds__(256) void gdn_ofin_kernel(
    const ushort* __restrict__ wQd, const ushort* __restrict__ wMp,
    const uint2* __restrict__ wDP, const uint2* __restrict__ wSP,
    float* __restrict__ o_t) {
  const int cidx = blockIdx.x;
  const int bh = cidx / NC_, nc = cidx - bh * NC_;
  const int b = bh / H_, h = bh - b * H_;
  const int tid = threadIdx.x;
  const int w = tid >> 6, l = tid & 63;
  const int lg = l >> 4, c16 = l & 15;
  const size_t t0 = (size_t)b * T_ + nc * C_;

  __shared__ uint2 sP[16384];  // 128 KB: full S_chk slot for this cidx
  {
    const char* gb = (const char*)(wSP + (size_t)cidx * 16384);
#pragma unroll
    for (int j = 0; j < 32; ++j) {
      const int i = w * 32 + j;
      gload_lds16(gb + i * 1024 + l * 16, (char*)&sP[0] + i * 1024);
    }
  }
  asm volatile("s_waitcnt vmcnt(0)" ::: "memory");
  __builtin_amdgcn_sched_barrier(0);
  __builtin_amdgcn_s_barrier();

  f32x4 acc[4][4];
#pragma unroll
  for (int mt = 0; mt < 4; ++mt)
#pragma unroll
    for (int nt = 0; nt < 4; ++nt) acc[mt][nt] = (f32x4){0.f, 0.f, 0.f, 0.f};

  // o += Qd * S_chk
#pragma unroll
  for (int nt = 0; nt < 4; ++nt) {
    const int cbwq = 4 * w + nt;
    uint2 SPl[16];
#pragma unroll
    for (int m2 = 0; m2 < 16; ++m2) SPl[m2] = sP[(cbwq * 16 + m2) * 64 + l];
#pragma unroll
    for (int kt = 0; kt < 8; ++kt) {
      const short8 Bf = buildB(SPl[2 * kt], SPl[2 * kt + 1], lg, c16);
#pragma unroll
      for (int mt = 0; mt < 4; ++mt) {
        const uint4 aq = *(const uint4*)&wQd[((t0 + 16 * mt + c16) * H_ + h) *
                                                 (size_t)DK_ +
                                             32 * kt + 8 * lg];
        acc[mt][nt] = __builtin_amdgcn_mfma_f32_16x16x32_bf16(
            u4_to_s8(aq), Bf, acc[mt][nt], 0, 0, 0);
      }
    }
  }
  // o += M * delta
  const ushort* Mb = wMp + (size_t)cidx * C_ * C_;
#pragma unroll
  for (int nt = 0; nt < 4; ++nt) {
    const int cbwq = 4 * w + nt;
    uint2 DPl[4];
#pragma unroll
    for (int mt2 = 0; mt2 < 4; ++mt2)
      DPl[mt2] = wDP[(((size_t)cidx * 16 + cbwq) * 4 + mt2) * 64 + l];
#pragma unroll
    for (int kt2 = 0; kt2 < 2; ++kt2) {
      const short8 Bf = buildB(DPl[2 * kt2], DPl[2 * kt2 + 1], lg, c16);
#pragma unroll
      for (int mt = 0; mt < 4; ++mt) {
        const uint4 am =
            *(const uint4*)&Mb[(16 * mt + c16) * C_ + 32 * kt2 + 8 * lg];
        acc[mt][nt] = __builtin_amdgcn_mfma_f32_16x16x32_bf16(
            u4_to_s8(am), Bf, acc[mt][nt], 0, 0, 0);
      }
    }
  }
  // store o (tiled fp32 over the first half of the slot)
#pragma unroll
  for (int mt = 0; mt < 4; ++mt)
#pragma unroll
    for (int nt = 0; nt < 4; ++nt)
#pragma unroll
      for (int r = 0; r < 4; ++r)
        o_t[(size_t)cidx * 32768 + (16 * mt + 4 * lg + r) * 256 +
            (4 * w + nt) * 16 + c16] = acc[mt][nt][r];
}

// ---------------------------------------------------------------------------
// Kernel 7: RMSNorm * norm_w * swish(gate), per-head GroupLinear
// (reads o from the per-chunk tiled layout)
// ---------------------------------------------------------------------------
__global__ __launch_bounds__(256) void gdn_out_kernel(
    const float* __restrict__ o_t, const float* __restrict__ sgate,
    const float* __restrict__ norm_w, const float* __restrict__ o_w,
    float* __restrict__ out) {
  const int tile = blockIdx.x;
  const int h = blockIdx.y;
  const int tid = threadIdx.x;
  const int lane = tid & 63;
  const int wid = tid >> 6;

  __shared__ float on[16][DV_];
  __shared__ float red[16][4];
  __shared__ float rms_s[16];
  __shared__ float sgs_s[16];

  const int bt0 = tile * 16;
  const int b = bt0 >> 11;          // / T_
  const int t0 = bt0 & (T_ - 1);
  const size_t slot =
      ((size_t)(b * H_ + h) * NC_ + (t0 >> 6)) * 32768 + (t0 & 63) * 256;

  float x[16];
#pragma unroll
  for (int tt = 0; tt < 16; ++tt) x[tt] = o_t[slot + tt * 256 + tid];

#pragma unroll
  for (int tt = 0; tt < 16; ++tt) {
    float ssv = x[tt] * x[tt];
    ssv += __shfl_xor(ssv, 1);
    ssv += __shfl_xor(ssv, 2);
    ssv += __shfl_xor(ssv, 4);
    ssv += __shfl_xor(ssv, 8);
    ssv += __shfl_xor(ssv, 16);
    ssv += __shfl_xor(ssv, 32);
    if (lane == 0) red[tt][wid] = ssv;
  }
  __syncthreads();
  if (tid < 16) {
    const float ms =
        (red[tid][0] + red[tid][1] + red[tid][2] + red[tid][3]) * (1.f / DV_);
    rms_s[tid] = rsqrtf(ms + 1e-5f);
    sgs_s[tid] = sgate[(size_t)(tile * 16 + tid) * H_ + h];
  }
  __syncthreads();

  const float nw = norm_w[tid];
#pragma unroll
  for (int tt = 0; tt < 16; ++tt) {
    on[tt][tid] = x[tt] * rms_s[tt] * nw * sgs_s[tt];
  }
  __syncthreads();

  float acc[16];
#pragma unroll
  for (int tt = 0; tt < 16; ++tt) acc[tt] = 0.f;

  const float* wp = o_w + (size_t)h * DV_ * DK_ + tid;
  for (int v4 = 0; v4 < DV_ / 4; ++v4) {
    const float w0 = wp[(4 * v4 + 0) * DK_];
    const float w1 = wp[(4 * v4 + 1) * DK_];
    const float w2 = wp[(4 * v4 + 2) * DK_];
    const float w3 = wp[(4 * v4 + 3) * DK_];
#pragma unroll
    for (int tt = 0; tt < 16; ++tt) {
      const float4 ov = *(const float4*)&on[tt][4 * v4];
      acc[tt] = fmaf(ov.x, w0,
                fmaf(ov.y, w1, fmaf(ov.z, w2, fmaf(ov.w, w3, acc[tt]))));
    }
  }

#pragma unroll
  for (int tt = 0; tt < 16; ++tt) {
    out[((size_t)(tile * 16 + tt) * H_ + h) * DK_ + tid] = acc[tt];
  }
}

// ---------------------------------------------------------------------------
extern "C" void kernel_launch(void* const* d_in, const int* in_sizes, int n_in,
                              void* d_out, int out_size, void* d_ws,
                              size_t ws_size, hipStream_t stream) {
  const float* hab = (const float*)d_in[0];
  const float* hg = (const float*)d_in[1];
  const float* q = (const float*)d_in[2];
  const float* k = (const float*)d_in[3];
  const float* v = (const float*)d_in[4];
  const float* b_w = (const float*)d_in[5];
  const float* a_w = (const float*)d_in[6];
  const float* A_log = (const float*)d_in[7];
  const float* dt_bias = (const float*)d_in[8];
  const float* g_w = (const float*)d_in[9];
  const float* norm_w = (const float*)d_in[10];
  const float* o_w = (const float*)d_in[11];
  float* out = (float*)d_out;

  float* ws = (float*)d_ws;
  const size_t NBT = (size_t)B_ * T_ * H_;  // 24576
  float* w_beta = ws;
  float* w_g = ws + NBT;
  float* w_sg = ws + 2 * NBT;
  float* w_sq = ws + 3 * NBT;
  float* w_sk = ws + 4 * NBT;
  float* w_G = ws + 5 * NBT;
  float* w_sqe = ws + 6 * NBT;
  ushort* w_Qd = (ushort*)(ws + 7 * NBT);          // 12,582,912 u16
  ushort* w_kT = w_Qd + (size_t)12582912;          // 6,291,456 u16
  ushort* w_W = w_kT + (size_t)6291456;            // 6,291,456 u16
  ushort* w_M = w_W + (size_t)6291456;             // 1,572,864 u16
  uint2* w_U = (uint2*)(w_M + (size_t)1572864);    // 1,572,864 uint2
  uint2* w_DP = w_U + (size_t)1572864;             // 1,572,864 uint2
  uint2* w_SPo = w_DP + (size_t)1572864;           // 6,291,456 uint2 (S_chk|o)

  hipLaunchKernelGGL(gdn_proj_kernel, dim3(B_ * T_), dim3(256), 0, stream,
                     hab, hg, b_w, a_w, g_w, A_log, dt_bias, w_beta, w_g, w_sg);
  hipLaunchKernelGGL(gdn_norm_kernel, dim3(B_ * T_ * H_ / 4), dim3(256), 0,
                     stream, q, k, w_sq, w_sk);
  hipLaunchKernelGGL(gdn_cum_kernel, dim3(B_ * H_), dim3(256), 0, stream,
                     w_g, w_sq, w_G, w_sqe);
  hipLaunchKernelGGL(gdn_qscale_kernel,
                     dim3((B_ * T_ * H_ * DK_) / (8 * 256)), dim3(256), 0,
                     stream, q, w_sqe, w_Qd);
  hipLaunchKernelGGL(gdn_ktrans_kernel, dim3(B_ * H_ * NC_), dim3(256), 0,
                     stream, k, w_sk, w_G, w_kT);
  hipLaunchKernelGGL(gdn_prep_kernel, dim3(B_ * H_ * NC_), dim3(256), 0,
                     stream, q, k, v, w_beta, w_sq, w_sk, w_G, w_U, w_W, w_M);
  hipLaunchKernelGGL(gdn_seq_kernel, dim3(B_ * H_ * 2), dim3(512), 0, stream,
                     w_kT, w_W, w_U, w_G, w_DP, w_SPo);
  hipLaunchKernelGGL(gdn_ofin_kernel, dim3(B_ * H_ * NC_), dim3(256), 0,
                     stream, w_Qd, w_M, w_DP, w_SPo, (float*)w_SPo);
  hipLaunchKernelGGL(gdn_out_kernel, dim3(B_ * T_ / 16, H_), dim3(256), 0,
                     stream, (const float*)w_SPo, w_sg, norm_w, o_w, out);
}

// Round 5
// 400.579 us; speedup vs baseline: 6.0775x; 1.0909x over previous
//
#include <hip/hip_runtime.h>
#include <hip/hip_bf16.h>
#include <math.h>

#define B_ 2
#define T_ 2048
#define H_ 6
#define DK_ 256
#define DV_ 256
#define HID_ 2048
#define C_ 64
#define NC_ 32

typedef __attribute__((ext_vector_type(8))) short short8;
typedef __attribute__((ext_vector_type(4))) float f32x4;

__device__ __forceinline__ unsigned rnebf(float f) {
  unsigned u = __float_as_uint(f);
  return (u + 0x7fffu + ((u >> 16) & 1u)) >> 16;
}
__device__ __forceinline__ unsigned pkbf(float lo, float hi) {
  return rnebf(lo) | (rnebf(hi) << 16);
}
__device__ __forceinline__ float bf2f(unsigned u16v) {
  return __uint_as_float((u16v & 0xffffu) << 16);
}
__device__ __forceinline__ short8 u4_to_s8(uint4 u) {
  union { uint4 u; short8 s; } c; c.u = u; return c.s;
}

// async global->LDS 16B per lane; LDS dest wave-uniform base + lane*16
__device__ __forceinline__ void gload_lds16(const void* g, void* l) {
  __builtin_amdgcn_global_load_lds(
      (const __attribute__((address_space(1))) unsigned int*)g,
      (__attribute__((address_space(3))) unsigned int*)l, 16, 0, 0);
}

// Build MFMA B-fragment (16x16x32 bf16) for k-tile from two C/D-layout packed
// mtiles Pe (even, rows 32kt..32kt+15) and Po (odd, rows +16..+31).
__device__ __forceinline__ short8 buildB(uint2 Pe, uint2 Po, int lg, int c16) {
  const int src0 = ((2 * (lg & 1)) << 4) | c16;
  const int src1 = src0 + 16;
  int e0 = __shfl((int)Pe.x, src0), o0 = __shfl((int)Po.x, src0);
  int e1 = __shfl((int)Pe.y, src0), o1 = __shfl((int)Po.y, src0);
  int e2 = __shfl((int)Pe.x, src1), o2 = __shfl((int)Po.x, src1);
  int e3 = __shfl((int)Pe.y, src1), o3 = __shfl((int)Po.y, src1);
  const bool lo2 = (lg < 2);
  union { int i[4]; short8 s; } u;
  u.i[0] = lo2 ? e0 : o0;
  u.i[1] = lo2 ? e1 : o1;
  u.i[2] = lo2 ? e2 : o2;
  u.i[3] = lo2 ? e3 : o3;
  return u.s;
}

// ---------------------------------------------------------------------------
// Kernel 1: fused projections (unchanged)
// ---------------------------------------------------------------------------
__global__ __launch_bounds__(256) void gdn_proj_kernel(
    const float* __restrict__ hab, const float* __restrict__ hg,
    const float* __restrict__ b_w, const float* __restrict__ a_w,
    const float* __restrict__ g_w, const float* __restrict__ A_log,
    const float* __restrict__ dt_bias,
    float* __restrict__ beta_o, float* __restrict__ g_o,
    float* __restrict__ sgate_o) {
  const int bt = blockIdx.x;
  const int tid = threadIdx.x;
  const int lane = tid & 63;
  const int wid = tid >> 6;

  const float* h1 = hab + (size_t)bt * HID_ + tid * 8;
  const float* h2 = hg + (size_t)bt * HID_ + tid * 8;
  const float4 xa = *(const float4*)(h1);
  const float4 xb = *(const float4*)(h1 + 4);
  const float4 ya = *(const float4*)(h2);
  const float4 yb = *(const float4*)(h2 + 4);

  float part[18];
#pragma unroll
  for (int n = 0; n < 6; ++n) {
    const float* wp = b_w + n * HID_ + tid * 8;
    const float4 w0 = *(const float4*)(wp);
    const float4 w1 = *(const float4*)(wp + 4);
    part[n] = xa.x * w0.x + xa.y * w0.y + xa.z * w0.z + xa.w * w0.w +
              xb.x * w1.x + xb.y * w1.y + xb.z * w1.z + xb.w * w1.w;
  }
#pragma unroll
  for (int n = 0; n < 6; ++n) {
    const float* wp = a_w + n * HID_ + tid * 8;
    const float4 w0 = *(const float4*)(wp);
    const float4 w1 = *(const float4*)(wp + 4);
    part[6 + n] = xa.x * w0.x + xa.y * w0.y + xa.z * w0.z + xa.w * w0.w +
                  xb.x * w1.x + xb.y * w1.y + xb.z * w1.z + xb.w * w1.w;
  }
#pragma unroll
  for (int n = 0; n < 6; ++n) {
    const float* wp = g_w + n * HID_ + tid * 8;
    const float4 w0 = *(const float4*)(wp);
    const float4 w1 = *(const float4*)(wp + 4);
    part[12 + n] = ya.x * w0.x + ya.y * w0.y + ya.z * w0.z + ya.w * w0.w +
                   yb.x * w1.x + yb.y * w1.y + yb.z * w1.z + yb.w * w1.w;
  }

  __shared__ float red[18][4];
#pragma unroll
  for (int i = 0; i < 18; ++i) {
    float x = part[i];
    x += __shfl_xor(x, 1);
    x += __shfl_xor(x, 2);
    x += __shfl_xor(x, 4);
    x += __shfl_xor(x, 8);
    x += __shfl_xor(x, 16);
    x += __shfl_xor(x, 32);
    if (lane == 0) red[i][wid] = x;
  }
  __syncthreads();

  if (tid < 18) {
    const float s = red[tid][0] + red[tid][1] + red[tid][2] + red[tid][3];
    if (tid < 6) {
      beta_o[(size_t)bt * H_ + tid] = 1.f / (1.f + __expf(-s));
    } else if (tid < 12) {
      const int n = tid - 6;
      const float x = s + dt_bias[n];
      const float sp = (x > 20.f) ? x : log1pf(__expf(x));
      g_o[(size_t)bt * H_ + n] = -__expf(A_log[n]) * sp;
    } else {
      const int n = tid - 12;
      sgate_o[(size_t)bt * H_ + n] = s / (1.f + __expf(-s));
    }
  }
}

// ---------------------------------------------------------------------------
// Kernel 2: q/k inverse L2 norms (unchanged)
// ---------------------------------------------------------------------------
__global__ __launch_bounds__(256) void gdn_norm_kernel(
    const float* __restrict__ q, const float* __restrict__ k,
    float* __restrict__ sq, float* __restrict__ sk) {
  const int gw = blockIdx.x * 4 + (threadIdx.x >> 6);
  const int lane = threadIdx.x & 63;

  const float4 qv = *(const float4*)(q + (size_t)gw * DK_ + lane * 4);
  const float4 kv = *(const float4*)(k + (size_t)gw * DK_ + lane * 4);
  float sums_q = qv.x * qv.x + qv.y * qv.y + qv.z * qv.z + qv.w * qv.w;
  float sums_k = kv.x * kv.x + kv.y * kv.y + kv.z * kv.z + kv.w * kv.w;
#pragma unroll
  for (int m = 1; m < 64; m <<= 1) {
    sums_q += __shfl_xor(sums_q, m);
    sums_k += __shfl_xor(sums_k, m);
  }
  if (lane == 0) {
    sq[gw] = rsqrtf(sums_q + 1e-6f) * 0.0625f;
    sk[gw] = rsqrtf(sums_k + 1e-6f);
  }
}

// ---------------------------------------------------------------------------
// Kernel 3: per-chunk inclusive cumsum of g; also sqe = sq*exp(G)
// ---------------------------------------------------------------------------
__global__ __launch_bounds__(256) void gdn_cum_kernel(
    const float* __restrict__ g, const float* __restrict__ sq,
    float* __restrict__ Gc, float* __restrict__ sqe) {
  const int bh = blockIdx.x;
  const int b = bh / H_, h = bh - b * H_;
  const int w = threadIdx.x >> 6, l = threadIdx.x & 63;
  for (int it = 0; it < 8; ++it) {
    const int nc = it * 4 + w;
    const int tg = nc * C_ + l;
    const size_t srow = ((size_t)b * T_ + tg) * H_ + h;
    float val = g[srow];
#pragma unroll
    for (int ofs = 1; ofs < 64; ofs <<= 1) {
      const float o = __shfl_up(val, ofs);
      if (l >= ofs) val += o;
    }
    Gc[(bh * NC_ + nc) * C_ + l] = val;
    sqe[srow] = sq[srow] * __expf(val);
  }
}

// ---------------------------------------------------------------------------
// Kernel 3b: Qd = q * sqe  (bf16, row-major [B,T,H,DK])
// ---------------------------------------------------------------------------
__global__ __launch_bounds__(256) void gdn_qscale_kernel(
    const float* __restrict__ q, const float* __restrict__ sqe,
    ushort* __restrict__ wQd) {
  const size_t i8 = (size_t)blockIdx.x * 256 + threadIdx.x;
  const size_t i0 = i8 * 8;
  const float s = sqe[i8 >> 5];
  const float4 a = *(const float4*)(q + i0);
  const float4 b = *(const float4*)(q + i0 + 4);
  uint4 o;
  o.x = pkbf(a.x * s, a.y * s);
  o.y = pkbf(a.z * s, a.w * s);
  o.z = pkbf(b.x * s, b.y * s);
  o.w = pkbf(b.z * s, b.w * s);
  *(uint4*)&wQd[i0] = o;
}

// ---------------------------------------------------------------------------
// Kernel 3c: kT tiles: [cidx][d(256)][t(64)] bf16, scale exp(gend-G)*sk folded
// ---------------------------------------------------------------------------
__global__ __launch_bounds__(256) void gdn_ktrans_kernel(
    const float* __restrict__ k, const float* __restrict__ sk,
    const float* __restrict__ Gc, ushort* __restrict__ wkT) {
  const int bid = blockIdx.x;
  const int bh = bid / NC_, nc = bid - bh * NC_;
  const int b = bh / H_, h = bh - b * H_;
  const int tid = threadIdx.x;
  const int cidx = bh * NC_ + nc;
  const size_t srow0 = ((size_t)b * T_ + nc * C_) * H_ + h;

  __shared__ ushort ldsT[256 * 68];
  const float gend = Gc[cidx * C_ + C_ - 1];

#pragma unroll
  for (int p = 0; p < 4; ++p) {
    const int t = p * 16 + (tid >> 4);
    const float scale =
        __expf(gend - Gc[cidx * C_ + t]) * sk[srow0 + (size_t)t * H_];
#pragma unroll
    for (int s = 0; s < 4; ++s) {
      const int col = 64 * s + 4 * (tid & 15);
      const float4 kv = *(const float4*)(k + (srow0 + (size_t)t * H_) * DK_ + col);
      ldsT[(col + 0) * 68 + t] = (ushort)rnebf(kv.x * scale);
      ldsT[(col + 1) * 68 + t] = (ushort)rnebf(kv.y * scale);
      ldsT[(col + 2) * 68 + t] = (ushort)rnebf(kv.z * scale);
      ldsT[(col + 3) * 68 + t] = (ushort)rnebf(kv.w * scale);
    }
  }
  __syncthreads();

  const int e = tid & 7;
#pragma unroll
  for (int p = 0; p < 8; ++p) {
    const int d = p * 32 + (tid >> 3);
    uint2 lo = *(uint2*)&ldsT[d * 68 + 8 * e];
    uint2 hi = *(uint2*)&ldsT[d * 68 + 8 * e + 4];
    uint4 o; o.x = lo.x; o.y = lo.y; o.z = hi.x; o.w = hi.y;
    *(uint4*)&wkT[((size_t)cidx * 256 + d) * C_ + 8 * e] = o;
  }
}

// ---------------------------------------------------------------------------
// Kernel 3d: o_wT[h][d][v] bf16 = transpose of o_w[h][v][d] fp32
// ---------------------------------------------------------------------------
__global__ __launch_bounds__(256) void gdn_owt_kernel(
    const float* __restrict__ o_w, ushort* __restrict__ owT) {
  const int h = blockIdx.x >> 2;
  const int db = (blockIdx.x & 3) * 64;
  const int tid = threadIdx.x;
  __shared__ ushort t[64][264];
#pragma unroll
  for (int it = 0; it < 16; ++it) {
    const int v = it * 16 + (tid >> 4);
    const int dl = 4 * (tid & 15);
    const float4 x = *(const float4*)&o_w[((size_t)h * 256 + v) * 256 + db + dl];
    t[dl + 0][v] = (ushort)rnebf(x.x);
    t[dl + 1][v] = (ushort)rnebf(x.y);
    t[dl + 2][v] = (ushort)rnebf(x.z);
    t[dl + 3][v] = (ushort)rnebf(x.w);
  }
  __syncthreads();
#pragma unroll
  for (int it = 0; it < 8; ++it) {
    const int idx = it * 256 + tid;
    const int d = idx >> 5;
    const int vv = (idx & 31) * 8;
    uint4 o;
    o.x = *(uint*)&t[d][vv + 0]; o.y = *(uint*)&t[d][vv + 2];
    o.z = *(uint*)&t[d][vv + 4]; o.w = *(uint*)&t[d][vv + 6];
    *(uint4*)&owT[((size_t)h * 256 + db + d) * 256 + vv] = o;
  }
}

// LDS XOR swizzle for prep tiles
__device__ __forceinline__ int swz4(int row, int c4) {
  return row * 256 + (((c4) ^ ((row >> 2) & 7)) << 2);
}
__device__ __forceinline__ int swzi(int row, int c) {
  return row * 256 + ((((c) >> 2) ^ ((row >> 2) & 7)) << 2) + ((c) & 3);
}

// ---------------------------------------------------------------------------
// Kernel 4 (parallel, per (b,h,chunk)): A, M, forward-substitution -> U, W.
// (unchanged from R3)
// ---------------------------------------------------------------------------
__global__ __launch_bounds__(256) void gdn_prep_kernel(
    const float* __restrict__ q, const float* __restrict__ k,
    const float* __restrict__ v, const float* __restrict__ beta,
    const float* __restrict__ sq, const float* __restrict__ sk,
    const float* __restrict__ Gc, uint2* __restrict__ wUp,
    ushort* __restrict__ wWp, ushort* __restrict__ wMp) {
  const int bid = blockIdx.x;
  const int bh = bid / NC_;
  const int nc = bid - bh * NC_;
  const int b = bh / H_, h = bh - b * H_;
  const int tid = threadIdx.x;
  const int w = tid >> 6, l = tid & 63;
  const int cidx = bh * NC_ + nc;

  __shared__ float kl[C_ * 256];
  __shared__ float xb[C_ * 256];
  __shared__ float AlT[C_][68];
  __shared__ float bG[C_], bB[C_];

  const size_t srow0 = ((size_t)b * T_ + nc * C_) * H_ + h;
  if (tid < C_) {
    bG[tid] = Gc[cidx * C_ + tid];
    bB[tid] = beta[srow0 + (size_t)tid * H_];
  }
#pragma unroll
  for (int rr = 0; rr < 16; ++rr) {
    const int row = rr * 4 + w;
    const size_t g0 = (srow0 + (size_t)row * H_) * DK_;
    const float skr = sk[srow0 + (size_t)row * H_];
    const float sqr = sq[srow0 + (size_t)row * H_];
    float4 kv = *(const float4*)(k + g0 + 4 * l);
    float4 qv = *(const float4*)(q + g0 + 4 * l);
    kv.x *= skr; kv.y *= skr; kv.z *= skr; kv.w *= skr;
    qv.x *= sqr; qv.y *= sqr; qv.z *= sqr; qv.w *= sqr;
    *(float4*)&kl[swz4(row, l)] = kv;
    *(float4*)&xb[swz4(row, l)] = qv;
  }
  __syncthreads();

  const int R = tid >> 4, Cc = tid & 15;
  // ---- M = masked(exp(Gt-Gi) * qn kn^T), i <= t  (bf16 row-major)
  {
    float acc[4][4];
#pragma unroll
    for (int a = 0; a < 4; ++a)
#pragma unroll
      for (int b2 = 0; b2 < 4; ++b2) acc[a][b2] = 0.f;
    for (int k4 = 0; k4 < 64; ++k4) {
      float4 qr[4], kr4[4];
#pragma unroll
      for (int a = 0; a < 4; ++a) qr[a] = *(float4*)&xb[swz4(4 * R + a, k4)];
#pragma unroll
      for (int b2 = 0; b2 < 4; ++b2)
        kr4[b2] = *(float4*)&kl[swz4(4 * Cc + b2, k4)];
#pragma unroll
      for (int a = 0; a < 4; ++a)
#pragma unroll
        for (int b2 = 0; b2 < 4; ++b2)
          acc[a][b2] += qr[a].x * kr4[b2].x + qr[a].y * kr4[b2].y +
                        qr[a].z * kr4[b2].z + qr[a].w * kr4[b2].w;
    }
    ushort* mbase = wMp + (size_t)cidx * C_ * C_;
#pragma unroll
    for (int a = 0; a < 4; ++a) {
      const int t = 4 * R + a;
      float tmp[4];
#pragma unroll
      for (int b2 = 0; b2 < 4; ++b2) {
        const int i = 4 * Cc + b2;
        tmp[b2] = (i <= t) ? acc[a][b2] * __expf(bG[t] - bG[i]) : 0.f;
      }
      uint2 ov; ov.x = pkbf(tmp[0], tmp[1]); ov.y = pkbf(tmp[2], tmp[3]);
      *(uint2*)&mbase[t * C_ + 4 * Cc] = ov;
    }
  }
  // ---- A (strictly lower), stored transposed
  if (Cc <= R) {
    float acc[4][4];
#pragma unroll
    for (int a = 0; a < 4; ++a)
#pragma unroll
      for (int b2 = 0; b2 < 4; ++b2) acc[a][b2] = 0.f;
    for (int k4 = 0; k4 < 64; ++k4) {
      float4 ar[4], br4[4];
#pragma unroll
      for (int a = 0; a < 4; ++a) ar[a] = *(float4*)&kl[swz4(4 * R + a, k4)];
#pragma unroll
      for (int b2 = 0; b2 < 4; ++b2)
        br4[b2] = *(float4*)&kl[swz4(4 * Cc + b2, k4)];
#pragma unroll
      for (int a = 0; a < 4; ++a)
#pragma unroll
        for (int b2 = 0; b2 < 4; ++b2)
          acc[a][b2] += ar[a].x * br4[b2].x + ar[a].y * br4[b2].y +
                        ar[a].z * br4[b2].z + ar[a].w * br4[b2].w;
    }
#pragma unroll
    for (int a = 0; a < 4; ++a) {
      const int t = 4 * R + a;
#pragma unroll
      for (int b2 = 0; b2 < 4; ++b2) {
        const int i = 4 * Cc + b2;
        AlT[i][t] = (i < t) ? bB[t] * __expf(bG[t] - bG[i]) * acc[a][b2] : 0.f;
      }
    }
  }
  __syncthreads();
#pragma unroll
  for (int rr = 0; rr < 16; ++rr) {
    const int row = rr * 4 + w;
    const float bbr = bB[row];
    const float sc = bbr * __expf(bG[row]);
    float4 kv = *(float4*)&kl[swz4(row, l)];
    kv.x *= sc; kv.y *= sc; kv.z *= sc; kv.w *= sc;
    *(float4*)&kl[swz4(row, l)] = kv;
    const size_t g0 = (srow0 + (size_t)row * H_) * DV_;
    float4 vv = *(const float4*)(v + g0 + 4 * l);
    vv.x *= bbr; vv.y *= bbr; vv.z *= bbr; vv.w *= bbr;
    *(float4*)&xb[swz4(row, l)] = vv;
  }
  __syncthreads();
  // ---- forward substitution (column tid on both RHS)
#pragma unroll
  for (int tb = 0; tb < 8; ++tb) {
    float xu[8], xw[8];
#pragma unroll
    for (int e = 0; e < 8; ++e) {
      xu[e] = xb[swzi(8 * tb + e, tid)];
      xw[e] = kl[swzi(8 * tb + e, tid)];
    }
    for (int i = 0; i < 8 * tb; ++i) {
      const float xui = xb[swzi(i, tid)];
      const float xwi = kl[swzi(i, tid)];
      float av[8];
      *(float4*)&av[0] = *(float4*)&AlT[i][8 * tb];
      *(float4*)&av[4] = *(float4*)&AlT[i][8 * tb + 4];
#pragma unroll
      for (int e = 0; e < 8; ++e) {
        xu[e] = fmaf(-av[e], xui, xu[e]);
        xw[e] = fmaf(-av[e], xwi, xw[e]);
      }
    }
#pragma unroll
    for (int e = 1; e < 8; ++e)
#pragma unroll
      for (int m = 0; m < 7; ++m)
        if (m < e) {
          const float am = AlT[8 * tb + m][8 * tb + e];
          xu[e] = fmaf(-am, xu[m], xu[e]);
          xw[e] = fmaf(-am, xw[m], xw[e]);
        }
#pragma unroll
    for (int e = 0; e < 8; ++e) {
      xb[swzi(8 * tb + e, tid)] = xu[e];
      kl[swzi(8 * tb + e, tid)] = xw[e];
    }
  }
  // ---- store W (bf16 row-major) and U (bf16 C/D-fragment packed pairs)
  {
    ushort* wb = wWp + (size_t)cidx * C_ * 256;
    for (int row = 0; row < C_; ++row)
      wb[row * 256 + tid] = (ushort)rnebf(kl[swzi(row, tid)]);
    const int cbw = tid >> 4, c16 = tid & 15;
#pragma unroll
    for (int mt = 0; mt < 4; ++mt) {
#pragma unroll
      for (int lgi = 0; lgi < 4; ++lgi) {
        const int r0 = 16 * mt + 4 * lgi;
        uint2 val;
        val.x = pkbf(xb[swzi(r0 + 0, tid)], xb[swzi(r0 + 1, tid)]);
        val.y = pkbf(xb[swzi(r0 + 2, tid)], xb[swzi(r0 + 3, tid)]);
        wUp[(((size_t)cidx * 16 + cbw) * 4 + mt) * 64 + (lgi << 4) + c16] = val;
      }
    }
  }
}

// ---------------------------------------------------------------------------
// Kernel 5 (sequential over chunks, MFMA + LDS pipeline):
// 24 blocks = (bh, half); 8 waves; wave owns S[256 x 16] (cbw = half*8+w).
// vmcnt counted so stores/prefetches stay in flight across chunks.
// ---------------------------------------------------------------------------
__global__ __launch_bounds__(512) void gdn_seq_kernel(
    const ushort* __restrict__ wkT, const ushort* __restrict__ wWp,
    const uint2* __restrict__ wUp, const float* __restrict__ Gc,
    uint2* __restrict__ wDP, uint2* __restrict__ wSP) {
  const int bid = blockIdx.x;
  const int bh = bid >> 1, half = bid & 1;
  const int tid = threadIdx.x;
  const int w = tid >> 6, l = tid & 63;
  const int lg = l >> 4, c16 = l & 15;
  const int cbw = half * 8 + w;
  const int xorv = (c16 & 7) << 4;

  __shared__ ushort sW[2][16384];  // 2 x 32 KB  (rows 512 B, XOR-swizzled)
  __shared__ ushort sK[2][16384];  // 2 x 32 KB  (rows 128 B, XOR-swizzled)
  __shared__ uint2 sU[2][2048];    // 2 x 16 KB  (linear)

  // ---- staging (each wave issues exactly 10 global_load_lds per chunk)
  auto stage = [&](int pp, int cidx2) {
    const char* gw_ = (const char*)(wWp + (size_t)cidx2 * 16384);
#pragma unroll
    for (int j = 0; j < 4; ++j) {
      const int i = w * 4 + j;
      const int row = 2 * i + (l >> 5);
      const int colb = ((l & 31) * 16) ^ ((row & 7) << 4);
      gload_lds16(gw_ + row * 512 + colb, (char*)&sW[pp][0] + i * 1024);
    }
    const char* gk_ = (const char*)(wkT + (size_t)cidx2 * 16384);
#pragma unroll
    for (int j = 0; j < 4; ++j) {
      const int i = w * 4 + j;
      const int row = 8 * i + (l >> 3);
      const int colb = ((l & 7) * 16) ^ ((row & 7) << 4);
      gload_lds16(gk_ + row * 128 + colb, (char*)&sK[pp][0] + i * 1024);
    }
    const char* gu_ = (const char*)wUp + (size_t)cidx2 * 32768 + half * 16384;
#pragma unroll
    for (int j = 0; j < 2; ++j) {
      const int i = w * 2 + j;
      gload_lds16(gu_ + i * 1024 + l * 16, (char*)&sU[pp][0] + i * 1024);
    }
  };

  f32x4 S[16];
#pragma unroll
  for (int m2 = 0; m2 < 16; ++m2) S[m2] = (f32x4){0.f, 0.f, 0.f, 0.f};

  stage(0, bh * NC_ + 0);
  stage(1, bh * NC_ + 1);
  float gcur = Gc[(bh * NC_) * C_ + C_ - 1];
  __builtin_amdgcn_sched_barrier(0);

  for (int nc = 0; nc < NC_; ++nc) {
    const int pp = nc & 1;
    const int cidx = bh * NC_ + nc;
    // wait for buf[pp]'s batch only: allow {prev stores(10) + next stage(10)}
    // to stay in flight; first/last chunks have only 10 newer ops.
    if (nc == 0 || nc == NC_ - 1)
      asm volatile("s_waitcnt vmcnt(10)" ::: "memory");
    else
      asm volatile("s_waitcnt vmcnt(20)" ::: "memory");
    __builtin_amdgcn_sched_barrier(0);
    __builtin_amdgcn_s_barrier();
    __builtin_amdgcn_sched_barrier(0);

    // pack S (chunk-start state) -> P; store checkpoint (uint4, contiguous)
    uint2 P[16];
#pragma unroll
    for (int m2 = 0; m2 < 16; ++m2) {
      P[m2].x = pkbf(S[m2][0], S[m2][1]);
      P[m2].y = pkbf(S[m2][2], S[m2][3]);
    }
    {
      uint4* sp4 = (uint4*)(wSP + (((size_t)cidx * 16 + cbw) * 64 + l) * 16);
#pragma unroll
      for (int i = 0; i < 8; ++i) {
        uint4 o; o.x = P[2 * i].x; o.y = P[2 * i].y;
        o.z = P[2 * i + 1].x; o.w = P[2 * i + 1].y;
        sp4[i] = o;
      }
    }
    float gnext = 0.f;
    if (nc + 1 < NC_) gnext = Gc[(cidx + 1) * C_ + C_ - 1];

    // GEMM1: p = W * S  (even/odd split accumulators -> 4-deep chain)
    f32x4 pe[4], po[4];
#pragma unroll
    for (int mt = 0; mt < 4; ++mt) {
      pe[mt] = (f32x4){0.f, 0.f, 0.f, 0.f};
      po[mt] = (f32x4){0.f, 0.f, 0.f, 0.f};
    }
    const char* sWb = (const char*)&sW[pp][0];
#pragma unroll
    for (int kt = 0; kt < 8; ++kt) {
      const short8 Bf = buildB(P[2 * kt], P[2 * kt + 1], lg, c16);
      const int colb = (64 * kt + 16 * lg) ^ xorv;
#pragma unroll
      for (int mt = 0; mt < 4; ++mt) {
        const uint4 aw = *(const uint4*)(sWb + (16 * mt + c16) * 512 + colb);
        if (kt & 1)
          po[mt] = __builtin_amdgcn_mfma_f32_16x16x32_bf16(u4_to_s8(aw), Bf,
                                                           po[mt], 0, 0, 0);
        else
          pe[mt] = __builtin_amdgcn_mfma_f32_16x16x32_bf16(u4_to_s8(aw), Bf,
                                                           pe[mt], 0, 0, 0);
      }
    }
    // delta = U - p
    uint2 DP[4];
#pragma unroll
    for (int mt = 0; mt < 4; ++mt) {
      const uint2 uu = sU[pp][(w * 4 + mt) * 64 + l];
      const float d0 = bf2f(uu.x) - (pe[mt][0] + po[mt][0]);
      const float d1 = bf2f(uu.x >> 16) - (pe[mt][1] + po[mt][1]);
      const float d2 = bf2f(uu.y) - (pe[mt][2] + po[mt][2]);
      const float d3 = bf2f(uu.y >> 16) - (pe[mt][3] + po[mt][3]);
      DP[mt].x = pkbf(d0, d1);
      DP[mt].y = pkbf(d2, d3);
    }
    {
      uint4* dp4 = (uint4*)(wDP + (((size_t)cidx * 16 + cbw) * 64 + l) * 4);
      uint4 o0; o0.x = DP[0].x; o0.y = DP[0].y; o0.z = DP[1].x; o0.w = DP[1].y;
      uint4 o1; o1.x = DP[2].x; o1.y = DP[2].y; o1.z = DP[3].x; o1.w = DP[3].y;
      dp4[0] = o0; dp4[1] = o1;
    }
    // S = lamC*S + Kd^T * delta
    const float lamC = __expf(gcur);
#pragma unroll
    for (int m2 = 0; m2 < 16; ++m2) {
      S[m2][0] *= lamC; S[m2][1] *= lamC; S[m2][2] *= lamC; S[m2][3] *= lamC;
    }
    const char* sKb = (const char*)&sK[pp][0];
#pragma unroll
    for (int kt = 0; kt < 2; ++kt) {
      const short8 Bd = buildB(DP[2 * kt], DP[2 * kt + 1], lg, c16);
      const int colb = (64 * kt + 16 * lg) ^ xorv;
#pragma unroll
      for (int m2 = 0; m2 < 16; ++m2) {
        const uint4 ak = *(const uint4*)(sKb + (16 * m2 + c16) * 128 + colb);
        S[m2] = __builtin_amdgcn_mfma_f32_16x16x32_bf16(u4_to_s8(ak), Bd,
                                                        S[m2], 0, 0, 0);
      }
    }
    gcur = gnext;
    // all waves done reading buf[pp]
    __builtin_amdgcn_sched_barrier(0);
    __builtin_amdgcn_s_barrier();
    __builtin_amdgcn_sched_barrier(0);
    if (nc + 2 < NC_) stage(pp, cidx + 2);
    __builtin_amdgcn_sched_barrier(0);
  }
}

// ---------------------------------------------------------------------------
// Kernel 6 (parallel, MFMA, fused epilogue): per (b,h,chunk):
//   o = Qd*S_chk + M*delta  (fp32 acc)
//   RMSNorm * norm_w * swish(gate) -> o_n bf16 in LDS
//   out = o_n @ o_wT  (MFMA GroupLinear), direct store to d_out
// ---------------------------------------------------------------------------
__global__ __launch_bounds__(256) void gdn_ofin_kernel(
    const ushort* __restrict__ wQd, const ushort* __restrict__ wMp,
    const uint2* __restrict__ wDP, const uint2* __restrict__ wSP,
    const float* __restrict__ sgate, const float* __restrict__ norm_w,
    const ushort* __restrict__ owT, float* __restrict__ out) {
  const int cidx = blockIdx.x;
  const int bh = cidx / NC_, nc = cidx - bh * NC_;
  const int b = bh / H_, h = bh - b * H_;
  const int tid = threadIdx.x;
  const int w = tid >> 6, l = tid & 63;
  const int lg = l >> 4, c16 = l & 15;
  const size_t t0 = (size_t)b * T_ + nc * C_;

  __shared__ ushort onl[64 * 256];  // 32 KB, rows 512 B XOR-swizzled
  __shared__ float red[64][4];
  __shared__ float rowf[64];

  f32x4 acc[4][4];
#pragma unroll
  for (int mt = 0; mt < 4; ++mt)
#pragma unroll
    for (int nt = 0; nt < 4; ++nt) acc[mt][nt] = (f32x4){0.f, 0.f, 0.f, 0.f};

  // ---- o += Qd * S_chk (S checkpoint read direct from global, contiguous)
#pragma unroll
  for (int nt = 0; nt < 4; ++nt) {
    const int cbwq = 4 * w + nt;
    uint2 SPl[16];
    const uint4* sp4 =
        (const uint4*)(wSP + (((size_t)cidx * 16 + cbwq) * 64 + l) * 16);
#pragma unroll
    for (int i = 0; i < 8; ++i) {
      const uint4 t4 = sp4[i];
      SPl[2 * i].x = t4.x; SPl[2 * i].y = t4.y;
      SPl[2 * i + 1].x = t4.z; SPl[2 * i + 1].y = t4.w;
    }
#pragma unroll
    for (int kt = 0; kt < 8; ++kt) {
      const short8 Bf = buildB(SPl[2 * kt], SPl[2 * kt + 1], lg, c16);
#pragma unroll
      for (int mt = 0; mt < 4; ++mt) {
        const uint4 aq = *(const uint4*)&wQd[((t0 + 16 * mt + c16) * H_ + h) *
                                                 (size_t)DK_ +
                                             32 * kt + 8 * lg];
        acc[mt][nt] = __builtin_amdgcn_mfma_f32_16x16x32_bf16(
            u4_to_s8(aq), Bf, acc[mt][nt], 0, 0, 0);
      }
    }
  }
  // ---- o += M * delta
  const ushort* Mb = wMp + (size_t)cidx * C_ * C_;
#pragma unroll
  for (int nt = 0; nt < 4; ++nt) {
    const int cbwq = 4 * w + nt;
    uint2 DPl[4];
    {
      const uint4* dp4 =
          (const uint4*)(wDP + (((size_t)cidx * 16 + cbwq) * 64 + l) * 4);
      const uint4 a0 = dp4[0], a1 = dp4[1];
      DPl[0].x = a0.x; DPl[0].y = a0.y; DPl[1].x = a0.z; DPl[1].y = a0.w;
      DPl[2].x = a1.x; DPl[2].y = a1.y; DPl[3].x = a1.z; DPl[3].y = a1.w;
    }
#pragma unroll
    for (int kt2 = 0; kt2 < 2; ++kt2) {
      const short8 Bf = buildB(DPl[2 * kt2], DPl[2 * kt2 + 1], lg, c16);
#pragma unroll
      for (int mt = 0; mt < 4; ++mt) {
        const uint4 am =
            *(const uint4*)&Mb[(16 * mt + c16) * C_ + 32 * kt2 + 8 * lg];
        acc[mt][nt] = __builtin_amdgcn_mfma_f32_16x16x32_bf16(
            u4_to_s8(am), Bf, acc[mt][nt], 0, 0, 0);
      }
    }
  }

  // ---- RMS reduce: per-row sum of squares across all 256 cols
  float ss[4][4];
#pragma unroll
  for (int mt = 0; mt < 4; ++mt)
#pragma unroll
    for (int r = 0; r < 4; ++r) {
      float s = acc[mt][0][r] * acc[mt][0][r];
      s = fmaf(acc[mt][1][r], acc[mt][1][r], s);
      s = fmaf(acc[mt][2][r], acc[mt][2][r], s);
      s = fmaf(acc[mt][3][r], acc[mt][3][r], s);
      s += __shfl_xor(s, 1);
      s += __shfl_xor(s, 2);
      s += __shfl_xor(s, 4);
      s += __shfl_xor(s, 8);
      ss[mt][r] = s;
    }
  if (c16 == 0) {
#pragma unroll
    for (int mt = 0; mt < 4; ++mt)
#pragma unroll
      for (int r = 0; r < 4; ++r) red[16 * mt + 4 * lg + r][w] = ss[mt][r];
  }
  __syncthreads();
  if (tid < 64) {
    const float ms =
        (red[tid][0] + red[tid][1] + red[tid][2] + red[tid][3]) * (1.f / DV_);
    const float sg = sgate[(t0 + tid) * H_ + h];
    rowf[tid] = rsqrtf(ms + 1e-5f) * sg;
  }
  __syncthreads();

  // ---- o_n = o * rowf * norm_w -> bf16 LDS (row-major, swizzled)
  {
    char* onb = (char*)onl;
#pragma unroll
    for (int mt = 0; mt < 4; ++mt) {
      float rf[4];
#pragma unroll
      for (int r = 0; r < 4; ++r) rf[r] = rowf[16 * mt + 4 * lg + r];
#pragma unroll
      for (int nt = 0; nt < 4; ++nt) {
        const int c = (4 * w + nt) * 16 + c16;
        const float nwv = norm_w[c];
#pragma unroll
        for (int r = 0; r < 4; ++r) {
          const int row = 16 * mt + 4 * lg + r;
          const float v = acc[mt][nt][r] * rf[r] * nwv;
          *(ushort*)(onb + row * 512 + ((2 * c) ^ ((row & 7) << 4))) =
              (ushort)rnebf(v);
        }
      }
    }
  }
  __syncthreads();

  // ---- out = o_n @ o_wT  (per wave: 64-row x 64-col block of out)
  f32x4 acc2[4][4];
#pragma unroll
  for (int mt = 0; mt < 4; ++mt)
#pragma unroll
    for (int nt2 = 0; nt2 < 4; ++nt2)
      acc2[mt][nt2] = (f32x4){0.f, 0.f, 0.f, 0.f};
  {
    const char* onb = (const char*)onl;
#pragma unroll
    for (int kt = 0; kt < 8; ++kt) {
      uint4 af[4];
#pragma unroll
      for (int mt = 0; mt < 4; ++mt)
        af[mt] = *(const uint4*)(onb + (16 * mt + c16) * 512 +
                                 ((64 * kt + 16 * lg) ^ ((c16 & 7) << 4)));
#pragma unroll
      for (int nt2 = 0; nt2 < 4; ++nt2) {
        const uint4 bf = *(const uint4*)&owT[((size_t)h * 256 +
                                              (4 * w + nt2) * 16 + c16) *
                                                 256 +
                                             32 * kt + 8 * lg];
#pragma unroll
        for (int mt = 0; mt < 4; ++mt)
          acc2[mt][nt2] = __builtin_amdgcn_mfma_f32_16x16x32_bf16(
              u4_to_s8(af[mt]), u4_to_s8(bf), acc2[mt][nt2], 0, 0, 0);
      }
    }
  }
#pragma unroll
  for (int mt = 0; mt < 4; ++mt)
#pragma unroll
    for (int nt2 = 0; nt2 < 4; ++nt2)
#pragma unroll
      for (int r = 0; r < 4; ++r)
        out[((t0 + 16 * mt + 4 * lg + r) * H_ + h) * (size_t)DK_ +
            (4 * w + nt2) * 16 + c16] = acc2[mt][nt2][r];
}

// ---------------------------------------------------------------------------
extern "C" void kernel_launch(void* const* d_in, const int* in_sizes, int n_in,
                              void* d_out, int out_size, void* d_ws,
                              size_t ws_size, hipStream_t stream) {
  const float* hab = (const float*)d_in[0];
  const float* hg = (const float*)d_in[1];
  const float* q = (const float*)d_in[2];
  const float* k = (const float*)d_in[3];
  const float* v = (const float*)d_in[4];
  const float* b_w = (const float*)d_in[5];
  const float* a_w = (const float*)d_in[6];
  const float* A_log = (const float*)d_in[7];
  const float* dt_bias = (const float*)d_in[8];
  const float* g_w = (const float*)d_in[9];
  const float* norm_w = (const float*)d_in[10];
  const float* o_w = (const float*)d_in[11];
  float* out = (float*)d_out;

  float* ws = (float*)d_ws;
  const size_t NBT = (size_t)B_ * T_ * H_;  // 24576
  float* w_beta = ws;
  float* w_g = ws + NBT;
  float* w_sg = ws + 2 * NBT;
  float* w_sq = ws + 3 * NBT;
  float* w_sk = ws + 4 * NBT;
  float* w_G = ws + 5 * NBT;
  float* w_sqe = ws + 6 * NBT;
  ushort* w_Qd = (ushort*)(ws + 7 * NBT);          // 12,582,912 u16
  ushort* w_kT = w_Qd + (size_t)12582912;          // 6,291,456 u16
  ushort* w_W = w_kT + (size_t)6291456;            // 6,291,456 u16
  ushort* w_M = w_W + (size_t)6291456;             // 1,572,864 u16
  uint2* w_U = (uint2*)(w_M + (size_t)1572864);    // 1,572,864 uint2
  uint2* w_DP = w_U + (size_t)1572864;             // 1,572,864 uint2
  uint2* w_SP = w_DP + (size_t)1572864;            // 6,291,456 uint2
  ushort* w_owT = (ushort*)(w_SP + (size_t)6291456);  // 393,216 u16

  hipLaunchKernelGGL(gdn_proj_kernel, dim3(B_ * T_), dim3(256), 0, stream,
                     hab, hg, b_w, a_w, g_w, A_log, dt_bias, w_beta, w_g, w_sg);
  hipLaunchKernelGGL(gdn_norm_kernel, dim3(B_ * T_ * H_ / 4), dim3(256), 0,
                     stream, q, k, w_sq, w_sk);
  hipLaunchKernelGGL(gdn_cum_kernel, dim3(B_ * H_), dim3(256), 0, stream,
                     w_g, w_sq, w_G, w_sqe);
  hipLaunchKernelGGL(gdn_qscale_kernel,
                     dim3((B_ * T_ * H_ * DK_) / (8 * 256)), dim3(256), 0,
                     stream, q, w_sqe, w_Qd);
  hipLaunchKernelGGL(gdn_ktrans_kernel, dim3(B_ * H_ * NC_), dim3(256), 0,
                     stream, k, w_sk, w_G, w_kT);
  hipLaunchKernelGGL(gdn_owt_kernel, dim3(H_ * 4), dim3(256), 0, stream,
                     o_w, w_owT);
  hipLaunchKernelGGL(gdn_prep_kernel, dim3(B_ * H_ * NC_), dim3(256), 0,
                     stream, q, k, v, w_beta, w_sq, w_sk, w_G, w_U, w_W, w_M);
  hipLaunchKernelGGL(gdn_seq_kernel, dim3(B_ * H_ * 2), dim3(512), 0, stream,
                     w_kT, w_W, w_U, w_G, w_DP, w_SP);
  hipLaunchKernelGGL(gdn_ofin_kernel, dim3(B_ * H_ * NC_), dim3(256), 0,
                     stream, w_Qd, w_M, w_DP, w_SP, w_sg, norm_w, w_owT, out);
}